// Round 2
// baseline (1509.144 us; speedup 1.0000x reference)
//
#include <hip/hip_runtime.h>
#include <hip/hip_bf16.h>

typedef __hip_bfloat16 bf16;

// Problem constants
#define UU 1024
#define BB 8
#define DD 512
#define HH 8
#define HD 64
#define RR 64
#define SS 16
#define MM 15
#define QQ 1104   // R + U + S
#define KVL 1103  // M + R + U
#define PEL 2047

#define GBM 128
#define GBN 128
#define GBK 16

// ---- dtype detection: is the float data bf16 (flag=1) or fp32 (flag=0)? ----
// Interpret the first 4096 half-words as bf16. True-bf16 normal data has
// |x| < ~16 (exp field <= ~131). fp32 data reinterpreted gives uniform-ish
// 16-bit patterns in the low halves: ~46% have exp field >= 137 (|x|>=2^10).
__global__ void detect_kernel(const void* probe, int* flag) {
  const unsigned short* p = (const unsigned short*)probe;
  int tid = threadIdx.x;
  int big = 0;
  for (int i = tid; i < 4096; i += 64) {
    int e = (p[i] >> 7) & 0xFF;
    if (e >= 137) big++;
  }
  #pragma unroll
  for (int off = 32; off; off >>= 1) big += __shfl_down(big, off);
  if (tid == 0) *flag = (big < 16) ? 1 : 0;
}

// Canonicalize a float input (either bf16 or fp32 per *flag) into bf16.
__global__ __launch_bounds__(256) void pack_kernel(const void* __restrict__ src,
                                                   bf16* __restrict__ dst, int n,
                                                   const int* __restrict__ flag) {
  int i = blockIdx.x * 256 + threadIdx.x;
  if (i >= n) return;
  if (*flag)
    dst[i] = ((const bf16*)src)[i];
  else
    dst[i] = __float2bfloat16(((const float*)src)[i]);
}

// out[m,n] = sum_k X[m,k] * W[n,k] (+ bias[n]);  X: M x K row-major, W: N x K row-major.
// If outf == nullptr, store bf16; else store bf16 when *outf==1 else fp32.
__global__ __launch_bounds__(256) void gemm_bias(
    const bf16* __restrict__ X, const bf16* __restrict__ W,
    const bf16* __restrict__ bias, void* __restrict__ out,
    int M, int N, int K, const int* __restrict__ outf) {
  __shared__ float As[GBK][GBM + 4];
  __shared__ float Bs[GBK][GBN + 4];
  const int bm = blockIdx.y * GBM, bn = blockIdx.x * GBN;
  const int tid = threadIdx.x;
  const int tx = tid & 15, ty = tid >> 4;
  float acc[8][8] = {};
  for (int k0 = 0; k0 < K; k0 += GBK) {
    #pragma unroll
    for (int i = tid; i < GBM * GBK; i += 256) {
      int cc = i & 15, r = i >> 4;
      int gm = bm + r;
      As[cc][r] = (gm < M) ? __bfloat162float(X[(size_t)gm * K + k0 + cc]) : 0.f;
    }
    #pragma unroll
    for (int i = tid; i < GBN * GBK; i += 256) {
      int cc = i & 15, r = i >> 4;
      int gn = bn + r;
      Bs[cc][r] = (gn < N) ? __bfloat162float(W[(size_t)gn * K + k0 + cc]) : 0.f;
    }
    __syncthreads();
    #pragma unroll
    for (int kk = 0; kk < GBK; ++kk) {
      float a[8], bv[8];
      #pragma unroll
      for (int i = 0; i < 8; ++i) a[i] = As[kk][ty * 8 + i];
      #pragma unroll
      for (int j = 0; j < 8; ++j) bv[j] = Bs[kk][tx * 8 + j];
      #pragma unroll
      for (int i = 0; i < 8; ++i)
        #pragma unroll
        for (int j = 0; j < 8; ++j) acc[i][j] += a[i] * bv[j];
    }
    __syncthreads();
  }
  const bool as_bf16 = (outf == nullptr) ? true : (*outf != 0);
  #pragma unroll
  for (int i = 0; i < 8; ++i) {
    int gm = bm + ty * 8 + i;
    if (gm >= M) continue;
    #pragma unroll
    for (int j = 0; j < 8; ++j) {
      int gn = bn + tx * 8 + j;
      if (gn >= N) continue;
      float v = acc[i][j];
      if (bias) v += __bfloat162float(bias[gn]);
      size_t o = (size_t)gm * N + gn;
      if (as_bf16) ((bf16*)out)[o] = __float2bfloat16(v);
      else         ((float*)out)[o] = v;
    }
  }
}

// One block per (q, b, h). Compact-column attention with analytic chunk mask.
__global__ __launch_bounds__(256) void attn_kernel(
    const bf16* __restrict__ query, const bf16* __restrict__ kvp,
    const bf16* __restrict__ pos, const bf16* __restrict__ pbu,
    const bf16* __restrict__ pbv, const int* __restrict__ lengths,
    bf16* __restrict__ attn) {
  const int idx = blockIdx.x;
  const int h = idx & 7;
  const int b = (idx >> 3) & 7;
  const int q = idx >> 6;

  int c, u = 0;
  bool is_utt = false;
  if (q < RR) {
    c = q >> 2;
  } else if (q < RR + UU) {
    u = q - RR;
    c = u >> 6;
    is_utt = true;
  } else {
    c = q - (RR + UU);
  }
  const int u0 = (c > 0 ? c - 1 : 0) << 6;
  const int nmem = c;                       // cols [0, c)
  const int rc0 = MM + (c << 2);            // cols [rc0, rc0+4)
  const int ut0 = MM + RR + u0;             // cols [ut0, 79 + (c+1)*64)
  const int nut = ((c + 1) << 6) - u0;      // 64 or 128
  const int ncols = nmem + 4 + nut;         // <= 147
  const int kvlim = MM + RR + lengths[b];   // cols >= kvlim padded out

  __shared__ float qu[HD], qv[HD];
  __shared__ float probs[256];
  __shared__ float red[8];
  __shared__ float part[4][HD];
  const int tid = threadIdx.x;

  if (tid < HD) {
    float qe = __bfloat162float(query[((size_t)(q * BB + b)) * DD + h * HD + tid]);
    qu[tid] = qe + __bfloat162float(pbu[h * HD + tid]);
    qv[tid] = qe + __bfloat162float(pbv[h * HD + tid]);
  }
  __syncthreads();

  float sc = -1e8f;
  if (tid < ncols) {
    int col = (tid < nmem) ? tid
             : (tid < nmem + 4 ? rc0 + (tid - nmem) : ut0 + (tid - nmem - 4));
    const bf16* kptr = kvp + ((size_t)(col * BB + b)) * (2 * DD) + h * HD;
    float acc = 0.f;
    #pragma unroll
    for (int e = 0; e < HD; ++e) acc += qu[e] * __bfloat162float(kptr[e]);
    if (is_utt && col >= MM + RR) {
      const bf16* pptr = pos + ((size_t)(UU - 1 - u + col - (MM + RR))) * DD + h * HD;
      float bd = 0.f;
      #pragma unroll
      for (int e = 0; e < HD; ++e) bd += qv[e] * __bfloat162float(pptr[e]);
      acc += bd;
    }
    sc = acc * 0.125f;  // scaling = 1/sqrt(64)
    if (col >= kvlim) sc = -1e8f;
  }

  // block-wide max (4 waves of 64)
  float m = sc;
  #pragma unroll
  for (int off = 32; off; off >>= 1) m = fmaxf(m, __shfl_down(m, off));
  if ((tid & 63) == 0) red[tid >> 6] = m;
  __syncthreads();
  const float mx = fmaxf(fmaxf(red[0], red[1]), fmaxf(red[2], red[3]));

  float p = __expf(sc - mx);
  probs[tid] = p;
  float s = p;
  #pragma unroll
  for (int off = 32; off; off >>= 1) s += __shfl_down(s, off);
  __syncthreads();  // everyone has read red before we overwrite it
  if ((tid & 63) == 0) red[tid >> 6] = s;
  __syncthreads();
  const float inv = 1.f / (red[0] + red[1] + red[2] + red[3]);

  // attn out: 4 groups of 64 lanes split the k loop
  const int e = tid & 63, g = tid >> 6;
  float acc = 0.f;
  for (int i = g; i < ncols; i += 4) {
    int col = (i < nmem) ? i
             : (i < nmem + 4 ? rc0 + (i - nmem) : ut0 + (i - nmem - 4));
    acc += probs[i] *
           __bfloat162float(kvp[((size_t)(col * BB + b)) * (2 * DD) + DD + h * HD + e]);
  }
  part[g][e] = acc;
  __syncthreads();
  if (tid < HD) {
    float o = (part[0][tid] + part[1][tid] + part[2][tid] + part[3][tid]) * inv;
    attn[((size_t)(q * BB + b)) * DD + h * HD + tid] = __float2bfloat16(o);
  }
}

__global__ __launch_bounds__(256) void clip_kernel(const bf16* __restrict__ attn,
                                                   void* __restrict__ out,
                                                   const int* __restrict__ flag) {
  const size_t base = (size_t)(RR + UU) * BB * DD;  // 8704*512
  int i = blockIdx.x * 256 + threadIdx.x;
  float v = __bfloat162float(attn[base + i]);
  v = fminf(fmaxf(v, -10.f), 10.f);
  if (*flag) ((bf16*)out)[base + i] = __float2bfloat16(v);
  else       ((float*)out)[base + i] = v;
}

static inline int cdiv(int a, int b) { return (a + b - 1) / b; }

extern "C" void kernel_launch(void* const* d_in, const int* in_sizes, int n_in,
                              void* d_out, int out_size, void* d_ws, size_t ws_size,
                              hipStream_t stream) {
  const void* utter  = d_in[0];
  const int*  lens   = (const int*)d_in[1];
  const void* rctx   = d_in[2];
  const void* summ   = d_in[3];
  const void* memry  = d_in[4];
  // d_in[5] attention_mask: computed analytically, never read
  const void* pose   = d_in[6];
  const void* W_kv   = d_in[7];
  const void* b_kv   = d_in[8];
  const void* W_q    = d_in[9];
  const void* b_q    = d_in[10];
  const void* W_out  = d_in[11];
  const void* b_out  = d_in[12];
  const void* W_pos  = d_in[13];
  const void* pbu    = d_in[14];
  const void* pbv    = d_in[15];

  const size_t SZ_RC  = (size_t)RR * BB * DD;   // 262144
  const size_t SZ_UT  = (size_t)UU * BB * DD;   // 4194304
  const size_t SZ_SM  = (size_t)SS * BB * DD;   // 65536
  const size_t SZ_MM  = (size_t)MM * BB * DD;   // 61440
  const size_t N_XQ   = SZ_RC + SZ_UT + SZ_SM;  // 4521984 (= QQ*BB*DD)
  const size_t N_XKV  = SZ_MM + SZ_RC + SZ_UT;  // 4517888 (= KVL*BB*DD)

  int*  flag  = (int*)d_ws;
  bf16* base  = (bf16*)((char*)d_ws + 64);
  bf16* Xq    = base;
  bf16* Xkv   = Xq + N_XQ;
  bf16* posec = Xkv + N_XKV;                 // 2047*512
  bf16* Wq    = posec + (size_t)PEL * DD;
  bf16* bq    = Wq + (size_t)DD * DD;
  bf16* Wkv   = bq + DD;
  bf16* bkv   = Wkv + (size_t)2 * DD * DD;
  bf16* Wout  = bkv + 2 * DD;
  bf16* bout  = Wout + (size_t)DD * DD;
  bf16* Wpos  = bout + DD;
  bf16* pbuc  = Wpos + (size_t)DD * DD;
  bf16* pbvc  = pbuc + DD;
  bf16* query = pbvc + DD;
  bf16* kvp   = query + N_XQ;                // (KVL*BB) x 1024, key|val
  bf16* pos   = kvp + N_XKV * 2;
  bf16* attn  = pos + (size_t)PEL * DD;

  detect_kernel<<<1, 64, 0, stream>>>(utter, flag);

  dim3 blk(256);
  auto pack = [&](const void* s, bf16* d, size_t n) {
    pack_kernel<<<dim3(cdiv((int)n, 256)), blk, 0, stream>>>(s, d, (int)n, flag);
  };
  pack(rctx,  Xq,                 SZ_RC);
  pack(utter, Xq + SZ_RC,         SZ_UT);
  pack(summ,  Xq + SZ_RC + SZ_UT, SZ_SM);
  pack(memry, Xkv,                 SZ_MM);
  pack(rctx,  Xkv + SZ_MM,         SZ_RC);
  pack(utter, Xkv + SZ_MM + SZ_RC, SZ_UT);
  pack(pose,  posec, (size_t)PEL * DD);
  pack(W_q,   Wq,   (size_t)DD * DD);
  pack(b_q,   bq,   DD);
  pack(W_kv,  Wkv,  (size_t)2 * DD * DD);
  pack(b_kv,  bkv,  2 * DD);
  pack(W_out, Wout, (size_t)DD * DD);
  pack(b_out, bout, DD);
  pack(W_pos, Wpos, (size_t)DD * DD);
  pack(pbu,   pbuc, DD);
  pack(pbv,   pbvc, DD);

  // query = Xq @ W_q^T + b_q : (8832, 512)
  gemm_bias<<<dim3(4, 69), blk, 0, stream>>>(Xq, Wq, bq, query, QQ * BB, DD, DD, nullptr);
  // kv = Xkv @ W_kv^T + b_kv : (8824, 1024)
  gemm_bias<<<dim3(8, 69), blk, 0, stream>>>(Xkv, Wkv, bkv, kvp, KVL * BB, 2 * DD, DD, nullptr);
  // pos = pos_emb @ W_pos^T : (2047, 512)
  gemm_bias<<<dim3(4, 16), blk, 0, stream>>>(posec, Wpos, nullptr, pos, PEL, DD, DD, nullptr);
  // attention: one block per (q, b, h)
  attn_kernel<<<dim3(QQ * BB * HH), blk, 0, stream>>>(query, kvp, pos, pbuc, pbvc, lens, attn);
  // out_ru = attn[:1088] @ W_out^T + b_out
  gemm_bias<<<dim3(4, 68), blk, 0, stream>>>(attn, Wout, bout, d_out, (RR + UU) * BB, DD, DD, flag);
  // out_mem = clip(attn[1088:], -10, 10)
  clip_kernel<<<dim3((SS * BB * DD) / 256), blk, 0, stream>>>(attn, d_out, flag);
}

// Round 3
// 742.955 us; speedup vs baseline: 2.0313x; 2.0313x over previous
//
#include <hip/hip_runtime.h>
#include <hip/hip_bf16.h>

typedef __hip_bfloat16 bf16;
typedef __attribute__((ext_vector_type(8))) short short8v;   // 8 bf16 (4 VGPRs)
typedef __attribute__((ext_vector_type(4))) float float4v;   // MFMA C/D frag

// Problem constants
#define UU 1024
#define BB 8
#define DD 512
#define HH 8
#define HD 64
#define RR 64
#define SS 16
#define MM 15
#define QQ 1104   // R + U + S
#define KVL 1103  // M + R + U
#define PEL 2047

// ---- dtype detection: is the float data bf16 (flag=1) or fp32 (flag=0)? ----
__global__ void detect_kernel(const void* probe, int* flag) {
  const unsigned short* p = (const unsigned short*)probe;
  int tid = threadIdx.x;
  int big = 0;
  for (int i = tid; i < 4096; i += 64) {
    int e = (p[i] >> 7) & 0xFF;
    if (e >= 137) big++;
  }
  #pragma unroll
  for (int off = 32; off; off >>= 1) big += __shfl_down(big, off);
  if (tid == 0) *flag = (big < 16) ? 1 : 0;
}

// Canonicalize a float input (either bf16 or fp32 per *flag) into bf16.
__global__ __launch_bounds__(256) void pack_kernel(const void* __restrict__ src,
                                                   bf16* __restrict__ dst, int n,
                                                   const int* __restrict__ flag) {
  int i = blockIdx.x * 256 + threadIdx.x;
  if (i >= n) return;
  if (*flag)
    dst[i] = ((const bf16*)src)[i];
  else
    dst[i] = __float2bfloat16(((const float*)src)[i]);
}

// ---- MFMA GEMM: out[m,n] = sum_k X[m,k] * W[n,k] (+ bias[n]) ----
// X: M x K row-major, W: N x K row-major (both bf16, K % 64 == 0, N % 128 == 0).
// Output bf16 if outf==nullptr, else bf16 when *outf==1 else fp32.
// 128x128 tile, BK=64, 4 waves, 4x4 16x16 MFMA tiles per wave.
__global__ __launch_bounds__(256) void gemm_mfma(
    const bf16* __restrict__ X, const bf16* __restrict__ W,
    const bf16* __restrict__ bias, void* __restrict__ out,
    int M, int N, int K, const int* __restrict__ outf) {
  __shared__ bf16 As[128 * 64];
  __shared__ bf16 Bs[128 * 64];
  const int tid = threadIdx.x;
  const int lane = tid & 63, wv = tid >> 6;
  const int wr = wv >> 1, wc = wv & 1;
  const int bm = blockIdx.y * 128, bn = blockIdx.x * 128;
  const int lrow = lane >> 3;            // 8 lanes per row (16B each)
  const int lk = (lane & 7) * 8;

  float4v acc[4][4] = {};

  for (int kb = 0; kb < K; kb += 64) {
    // stage A rows [wv*32, wv*32+32), 4 chunks of 8 rows (1 KB per instr)
    #pragma unroll
    for (int i = 0; i < 4; ++i) {
      int r = wv * 32 + i * 8 + lrow;
      int gm = bm + r; if (gm > M - 1) gm = M - 1;   // clamp tail rows
      const bf16* src = X + (size_t)gm * K + kb + lk;
      __builtin_amdgcn_global_load_lds(
          (const __attribute__((address_space(1))) void*)src,
          (__attribute__((address_space(3))) void*)&As[(wv * 32 + i * 8) * 64],
          16, 0, 0);
    }
    #pragma unroll
    for (int i = 0; i < 4; ++i) {
      int r = wv * 32 + i * 8 + lrow;
      const bf16* src = W + (size_t)(bn + r) * K + kb + lk;
      __builtin_amdgcn_global_load_lds(
          (const __attribute__((address_space(1))) void*)src,
          (__attribute__((address_space(3))) void*)&Bs[(wv * 32 + i * 8) * 64],
          16, 0, 0);
    }
    __syncthreads();
    #pragma unroll
    for (int ki = 0; ki < 2; ++ki) {
      short8v a[4], bq[4];
      #pragma unroll
      for (int t = 0; t < 4; ++t)
        a[t] = *(const short8v*)&As[(wr * 64 + t * 16 + (lane & 15)) * 64 +
                                    ki * 32 + (lane >> 4) * 8];
      #pragma unroll
      for (int t = 0; t < 4; ++t)
        bq[t] = *(const short8v*)&Bs[(wc * 64 + t * 16 + (lane & 15)) * 64 +
                                     ki * 32 + (lane >> 4) * 8];
      #pragma unroll
      for (int mt = 0; mt < 4; ++mt)
        #pragma unroll
        for (int nt = 0; nt < 4; ++nt)
          acc[mt][nt] = __builtin_amdgcn_mfma_f32_16x16x32_bf16(
              a[mt], bq[nt], acc[mt][nt], 0, 0, 0);
    }
    __syncthreads();
  }

  const bool as_bf16 = (outf == nullptr) ? true : (*outf != 0);
  const int quad = lane >> 4, cn = lane & 15;
  #pragma unroll
  for (int mt = 0; mt < 4; ++mt) {
    #pragma unroll
    for (int r = 0; r < 4; ++r) {
      int gm = bm + wr * 64 + mt * 16 + quad * 4 + r;
      if (gm >= M) continue;
      #pragma unroll
      for (int nt = 0; nt < 4; ++nt) {
        int gn = bn + wc * 64 + nt * 16 + cn;
        float v = acc[mt][nt][r];
        if (bias) v += __bfloat162float(bias[gn]);
        size_t o = (size_t)gm * N + gn;
        if (as_bf16) ((bf16*)out)[o] = __float2bfloat16(v);
        else         ((float*)out)[o] = v;
      }
    }
  }
}

// ---- attention helpers: unpack 2/8 bf16 and dot with fp32 ----
__device__ __forceinline__ float2 bfp(unsigned int u) {
  return make_float2(__uint_as_float(u << 16), __uint_as_float(u & 0xffff0000u));
}
__device__ __forceinline__ float dot8(uint4 pk, const float4* q) {
  float2 a0 = bfp(pk.x), a1 = bfp(pk.y), a2 = bfp(pk.z), a3 = bfp(pk.w);
  float4 q0 = q[0], q1 = q[1];
  return a0.x * q0.x + a0.y * q0.y + a1.x * q0.z + a1.y * q0.w +
         a2.x * q1.x + a2.y * q1.y + a3.x * q1.z + a3.y * q1.w;
}

// One block (192 thr = 3 waves) per (q, b, h). Compact-column attention.
__global__ __launch_bounds__(192) void attn_kernel(
    const bf16* __restrict__ query, const bf16* __restrict__ kvp,
    const bf16* __restrict__ pos, const bf16* __restrict__ pbu,
    const bf16* __restrict__ pbv, const int* __restrict__ lengths,
    bf16* __restrict__ attn) {
  const int idx = blockIdx.x;
  const int h = idx & 7;
  const int b = (idx >> 3) & 7;
  const int q = idx >> 6;

  int c, u = 0;
  bool is_utt = false;
  if (q < RR) {
    c = q >> 2;
  } else if (q < RR + UU) {
    u = q - RR;
    c = u >> 6;
    is_utt = true;
  } else {
    c = q - (RR + UU);
  }
  const int u0 = (c > 0 ? c - 1 : 0) << 6;
  const int nmem = c;
  const int rc0 = MM + (c << 2);
  const int ut0 = MM + RR + u0;
  const int nut = ((c + 1) << 6) - u0;      // 64 or 128
  const int ncols = nmem + 4 + nut;         // <= 147
  const int kvlim = MM + RR + lengths[b];

  __shared__ float qu[HD], qv[HD];
  __shared__ float probs[192];
  __shared__ float red[3];
  __shared__ float part[3][HD];
  const int tid = threadIdx.x;

  if (tid < HD) {
    float qe = __bfloat162float(query[((size_t)(q * BB + b)) * DD + h * HD + tid]);
    qu[tid] = qe + __bfloat162float(pbu[h * HD + tid]);
    qv[tid] = qe + __bfloat162float(pbv[h * HD + tid]);
  }
  __syncthreads();

  float sc = -1e8f;
  if (tid < ncols) {
    int col = (tid < nmem) ? tid
             : (tid < nmem + 4 ? rc0 + (tid - nmem) : ut0 + (tid - nmem - 4));
    const uint4* kptr = (const uint4*)(kvp + ((size_t)(col * BB + b)) * (2 * DD) + h * HD);
    float acc = 0.f;
    #pragma unroll
    for (int i = 0; i < 8; ++i) acc += dot8(kptr[i], (const float4*)&qu[i * 8]);
    if (is_utt && col >= MM + RR) {
      const uint4* pptr =
          (const uint4*)(pos + (size_t)(UU - 1 - u + col - (MM + RR)) * DD + h * HD);
      float bd = 0.f;
      #pragma unroll
      for (int i = 0; i < 8; ++i) bd += dot8(pptr[i], (const float4*)&qv[i * 8]);
      acc += bd;
    }
    sc = acc * 0.125f;
    if (col >= kvlim) sc = -1e8f;
  }

  // block max over 3 waves
  float m = sc;
  #pragma unroll
  for (int off = 32; off; off >>= 1) m = fmaxf(m, __shfl_down(m, off));
  if ((tid & 63) == 0) red[tid >> 6] = m;
  __syncthreads();
  const float mx = fmaxf(fmaxf(red[0], red[1]), red[2]);

  float p = __expf(sc - mx);
  probs[tid] = p;
  float s = p;
  #pragma unroll
  for (int off = 32; off; off >>= 1) s += __shfl_down(s, off);
  __syncthreads();
  if ((tid & 63) == 0) red[tid >> 6] = s;
  __syncthreads();
  const float inv = 1.f / (red[0] + red[1] + red[2]);

  const int e = tid & 63, g = tid >> 6;
  float acc = 0.f;
  for (int i = g; i < ncols; i += 3) {
    int col = (i < nmem) ? i
             : (i < nmem + 4 ? rc0 + (i - nmem) : ut0 + (i - nmem - 4));
    acc += probs[i] *
           __bfloat162float(kvp[((size_t)(col * BB + b)) * (2 * DD) + DD + h * HD + e]);
  }
  part[g][e] = acc;
  __syncthreads();
  if (tid < HD) {
    float o = (part[0][tid] + part[1][tid] + part[2][tid]) * inv;
    attn[((size_t)(q * BB + b)) * DD + h * HD + tid] = __float2bfloat16(o);
  }
}

__global__ __launch_bounds__(256) void clip_kernel(const bf16* __restrict__ attn,
                                                   void* __restrict__ out,
                                                   const int* __restrict__ flag) {
  const size_t base = (size_t)(RR + UU) * BB * DD;
  int i = blockIdx.x * 256 + threadIdx.x;
  float v = __bfloat162float(attn[base + i]);
  v = fminf(fmaxf(v, -10.f), 10.f);
  if (*flag) ((bf16*)out)[base + i] = __float2bfloat16(v);
  else       ((float*)out)[base + i] = v;
}

static inline int cdiv(int a, int b) { return (a + b - 1) / b; }

extern "C" void kernel_launch(void* const* d_in, const int* in_sizes, int n_in,
                              void* d_out, int out_size, void* d_ws, size_t ws_size,
                              hipStream_t stream) {
  const void* utter  = d_in[0];
  const int*  lens   = (const int*)d_in[1];
  const void* rctx   = d_in[2];
  const void* summ   = d_in[3];
  const void* memry  = d_in[4];
  // d_in[5] attention_mask: computed analytically, never read
  const void* pose   = d_in[6];
  const void* W_kv   = d_in[7];
  const void* b_kv   = d_in[8];
  const void* W_q    = d_in[9];
  const void* b_q    = d_in[10];
  const void* W_out  = d_in[11];
  const void* b_out  = d_in[12];
  const void* W_pos  = d_in[13];
  const void* pbu    = d_in[14];
  const void* pbv    = d_in[15];

  const size_t SZ_RC  = (size_t)RR * BB * DD;
  const size_t SZ_UT  = (size_t)UU * BB * DD;
  const size_t SZ_SM  = (size_t)SS * BB * DD;
  const size_t SZ_MM  = (size_t)MM * BB * DD;
  const size_t N_XQ   = SZ_RC + SZ_UT + SZ_SM;  // QQ*BB*DD
  const size_t N_XKV  = SZ_MM + SZ_RC + SZ_UT;  // KVL*BB*DD

  int*  flag  = (int*)d_ws;
  bf16* base  = (bf16*)((char*)d_ws + 64);
  bf16* Xq    = base;
  bf16* Xkv   = Xq + N_XQ;
  bf16* posec = Xkv + N_XKV;
  bf16* Wq    = posec + (size_t)PEL * DD;
  bf16* bq    = Wq + (size_t)DD * DD;
  bf16* Wkv   = bq + DD;
  bf16* bkv   = Wkv + (size_t)2 * DD * DD;
  bf16* Wout  = bkv + 2 * DD;
  bf16* bout  = Wout + (size_t)DD * DD;
  bf16* Wpos  = bout + DD;
  bf16* pbuc  = Wpos + (size_t)DD * DD;
  bf16* pbvc  = pbuc + DD;
  bf16* query = pbvc + DD;
  bf16* kvp   = query + N_XQ;                // (KVL*BB) x 1024, key|val
  bf16* pos   = kvp + N_XKV * 2;
  bf16* attn  = pos + (size_t)PEL * DD;

  detect_kernel<<<1, 64, 0, stream>>>(utter, flag);

  dim3 blk(256);
  auto pack = [&](const void* s, bf16* d, size_t n) {
    pack_kernel<<<dim3(cdiv((int)n, 256)), blk, 0, stream>>>(s, d, (int)n, flag);
  };
  pack(rctx,  Xq,                 SZ_RC);
  pack(utter, Xq + SZ_RC,         SZ_UT);
  pack(summ,  Xq + SZ_RC + SZ_UT, SZ_SM);
  pack(memry, Xkv,                 SZ_MM);
  pack(rctx,  Xkv + SZ_MM,         SZ_RC);
  pack(utter, Xkv + SZ_MM + SZ_RC, SZ_UT);
  pack(pose,  posec, (size_t)PEL * DD);
  pack(W_q,   Wq,   (size_t)DD * DD);
  pack(b_q,   bq,   DD);
  pack(W_kv,  Wkv,  (size_t)2 * DD * DD);
  pack(b_kv,  bkv,  2 * DD);
  pack(W_out, Wout, (size_t)DD * DD);
  pack(b_out, bout, DD);
  pack(W_pos, Wpos, (size_t)DD * DD);
  pack(pbu,   pbuc, DD);
  pack(pbv,   pbvc, DD);

  // query = Xq @ W_q^T + b_q : (8832, 512)
  gemm_mfma<<<dim3(4, 69), blk, 0, stream>>>(Xq, Wq, bq, query, QQ * BB, DD, DD, nullptr);
  // kv = Xkv @ W_kv^T + b_kv : (8824, 1024)
  gemm_mfma<<<dim3(8, 69), blk, 0, stream>>>(Xkv, Wkv, bkv, kvp, KVL * BB, 2 * DD, DD, nullptr);
  // pos = pos_emb @ W_pos^T : (2047, 512)
  gemm_mfma<<<dim3(4, 16), blk, 0, stream>>>(posec, Wpos, nullptr, pos, PEL, DD, DD, nullptr);
  // attention: one block per (q, b, h)
  attn_kernel<<<dim3(QQ * BB * HH), dim3(192), 0, stream>>>(query, kvp, pos, pbuc, pbvc,
                                                            lens, attn);
  // out_ru = attn[:1088] @ W_out^T + b_out
  gemm_mfma<<<dim3(4, 68), blk, 0, stream>>>(attn, Wout, bout, d_out, (RR + UU) * BB, DD, DD, flag);
  // out_mem = clip(attn[1088:], -10, 10)
  clip_kernel<<<dim3((SS * BB * DD) / 256), blk, 0, stream>>>(attn, d_out, flag);
}

// Round 4
// 281.672 us; speedup vs baseline: 5.3578x; 2.6377x over previous
//
#include <hip/hip_runtime.h>
#include <hip/hip_bf16.h>

typedef __hip_bfloat16 bf16;
typedef __attribute__((ext_vector_type(8))) short short8v;   // 8 bf16 (4 VGPRs)
typedef __attribute__((ext_vector_type(4))) float float4v;   // MFMA C/D frag

// Problem constants
#define UU 1024
#define BB 8
#define DD 512
#define HH 8
#define HD 64
#define RR 64
#define SS 16
#define MM 15
#define QQ 1104   // R + U + S
#define KVL 1103  // M + R + U
#define PEL 2047

#define AS1 __attribute__((address_space(1)))
#define AS3 __attribute__((address_space(3)))

// ---- dtype detection: is the float data bf16 (flag=1) or fp32 (flag=0)? ----
__global__ void detect_kernel(const void* probe, int* flag) {
  const unsigned short* p = (const unsigned short*)probe;
  int tid = threadIdx.x;
  int big = 0;
  for (int i = tid; i < 4096; i += 64) {
    int e = (p[i] >> 7) & 0xFF;
    if (e >= 137) big++;
  }
  #pragma unroll
  for (int off = 32; off; off >>= 1) big += __shfl_down(big, off);
  if (tid == 0) *flag = (big < 16) ? 1 : 0;
}

// ---- fused canonicalization of all 16 float inputs into bf16 workspace ----
struct PackDesc {
  const void* src[16];
  unsigned int srcoff[16];   // element offset into src
  unsigned int dstoff[16];   // element offset into dst base
  unsigned int cum[17];      // cumulative 8-element chunks
};

__device__ __forceinline__ float lo16(unsigned u) { return __uint_as_float(u << 16); }
__device__ __forceinline__ float hi16(unsigned u) { return __uint_as_float(u & 0xffff0000u); }
__device__ __forceinline__ unsigned pk2(float a, float b) {
  unsigned short x = __builtin_bit_cast(unsigned short, __float2bfloat16(a));
  unsigned short y = __builtin_bit_cast(unsigned short, __float2bfloat16(b));
  return (unsigned)x | ((unsigned)y << 16);
}

__global__ __launch_bounds__(256) void pack_all(PackDesc d, bf16* base,
                                                const int* __restrict__ flag,
                                                int nchunks) {
  int g = blockIdx.x * 256 + threadIdx.x;
  if (g >= nchunks) return;
  int s = 0;
  #pragma unroll
  for (int i = 1; i < 17; ++i) s += (g >= d.cum[i]) ? 1 : 0;
  unsigned local = (g - d.cum[s]) * 8u;
  bf16* dst = base + d.dstoff[s] + local;
  if (*flag) {
    const uint4 v = *(const uint4*)((const bf16*)d.src[s] + d.srcoff[s] + local);
    *(uint4*)dst = v;
  } else {
    const float* fp = (const float*)d.src[s] + d.srcoff[s] + local;
    uint4 o;
    o.x = pk2(fp[0], fp[1]);
    o.y = pk2(fp[2], fp[3]);
    o.z = pk2(fp[4], fp[5]);
    o.w = pk2(fp[6], fp[7]);
    *(uint4*)dst = o;
  }
}

// ---- MFMA GEMM: out[m,n] = sum_k X[m,k] * W[n,k] (+ bias[n]) ----
__global__ __launch_bounds__(256) void gemm_mfma(
    const bf16* __restrict__ X, const bf16* __restrict__ W,
    const bf16* __restrict__ bias, void* __restrict__ out,
    int M, int N, int K, const int* __restrict__ outf) {
  __shared__ bf16 As[128 * 64];
  __shared__ bf16 Bs[128 * 64];
  const int tid = threadIdx.x;
  const int lane = tid & 63, wv = tid >> 6;
  const int wr = wv >> 1, wc = wv & 1;
  const int bm = blockIdx.y * 128, bn = blockIdx.x * 128;
  const int lrow = lane >> 3;
  const int lk = (lane & 7) * 8;

  float4v acc[4][4] = {};

  for (int kb = 0; kb < K; kb += 64) {
    #pragma unroll
    for (int i = 0; i < 4; ++i) {
      int r = wv * 32 + i * 8 + lrow;
      int gm = bm + r; if (gm > M - 1) gm = M - 1;
      const bf16* src = X + (size_t)gm * K + kb + lk;
      __builtin_amdgcn_global_load_lds((const AS1 void*)src,
                                       (AS3 void*)&As[(wv * 32 + i * 8) * 64], 16, 0, 0);
    }
    #pragma unroll
    for (int i = 0; i < 4; ++i) {
      int r = wv * 32 + i * 8 + lrow;
      const bf16* src = W + (size_t)(bn + r) * K + kb + lk;
      __builtin_amdgcn_global_load_lds((const AS1 void*)src,
                                       (AS3 void*)&Bs[(wv * 32 + i * 8) * 64], 16, 0, 0);
    }
    __syncthreads();
    #pragma unroll
    for (int ki = 0; ki < 2; ++ki) {
      short8v a[4], bq[4];
      #pragma unroll
      for (int t = 0; t < 4; ++t)
        a[t] = *(const short8v*)&As[(wr * 64 + t * 16 + (lane & 15)) * 64 +
                                    ki * 32 + (lane >> 4) * 8];
      #pragma unroll
      for (int t = 0; t < 4; ++t)
        bq[t] = *(const short8v*)&Bs[(wc * 64 + t * 16 + (lane & 15)) * 64 +
                                     ki * 32 + (lane >> 4) * 8];
      #pragma unroll
      for (int mt = 0; mt < 4; ++mt)
        #pragma unroll
        for (int nt = 0; nt < 4; ++nt)
          acc[mt][nt] = __builtin_amdgcn_mfma_f32_16x16x32_bf16(
              a[mt], bq[nt], acc[mt][nt], 0, 0, 0);
    }
    __syncthreads();
  }

  const bool as_bf16 = (outf == nullptr) ? true : (*outf != 0);
  const int quad = lane >> 4, cn = lane & 15;
  #pragma unroll
  for (int mt = 0; mt < 4; ++mt) {
    #pragma unroll
    for (int r = 0; r < 4; ++r) {
      int gm = bm + wr * 64 + mt * 16 + quad * 4 + r;
      if (gm >= M) continue;
      #pragma unroll
      for (int nt = 0; nt < 4; ++nt) {
        int gn = bn + wc * 64 + nt * 16 + cn;
        float v = acc[mt][nt][r];
        if (bias) v += __bfloat162float(bias[gn]);
        size_t o = (size_t)gm * N + gn;
        if (as_bf16) ((bf16*)out)[o] = __float2bfloat16(v);
        else         ((float*)out)[o] = v;
      }
    }
  }
}

// ---- MFMA chunk attention: one block per (c, b, h) ----
// Rows m: 0..63 = utterance u=64c+m, 64..67 = RC 4c+(m-64), 68 = summary c.
// Cols (compact): [0,c) mem, [c,c+4) RC, [c+4, c+4+nut) utterance window.
__device__ __forceinline__ int gcol(int row, int c, int u0, int ncols) {
  if (row < c) return row;
  if (row < c + 4) return 15 + 4 * c + (row - c);
  if (row < ncols) return 79 + u0 + (row - c - 4);
  return 0;
}

__global__ __launch_bounds__(256, 2) void attn_chunk(
    const bf16* __restrict__ query, const bf16* __restrict__ kvp,
    const bf16* __restrict__ pos, const bf16* __restrict__ pbu,
    const bf16* __restrict__ pbv, const int* __restrict__ lengths,
    bf16* __restrict__ attn) {
  __shared__ char lds[65536];
  bf16* Vs   = (bf16*)(lds);           // [152][64]  staged early
  bf16* Aqu  = (bf16*)(lds + 19456);   // [80][64]   staged early
  bf16* Kt   = (bf16*)(lds + 29696);   // [152][64]  staged after E GEMM
  bf16* Aqv  = (bf16*)(lds + 32768);   // [64][64]   early (dies after E GEMM)
  bf16* Psl  = (bf16*)(lds + 40960);   // [192][64]  early (dies after E GEMM)
  bf16* Eb   = (bf16*)(lds + 49152);   // [64][128]  after E GEMM
  bf16* Pp   = (bf16*)(lds + 19456);   // [80][168]  softmax phase (over Aqu/Kt head)
  float* wred  = (float*)(lds + 46336); // [80][4]   after S GEMM (over Kt tail)
  float* rstat = (float*)(lds + 47616); // [80]

  const int idx = blockIdx.x;
  const int h = idx & 7, b = (idx >> 3) & 7, c = idx >> 6;
  const int u0 = c ? (c - 1) * 64 : 0;
  const int nut = c ? 128 : 64;
  const int ncols = c + 4 + nut;
  const int q0 = c ? 63 : 127;     // p = q0 - m + jl
  const int tid = threadIdx.x, lane = tid & 63, wv = tid >> 6;
  const int quad = lane >> 4, l15 = lane & 15;
  const int lenlim = lengths[b] - u0;  // utt col jl >= lenlim -> masked

  // ---- stage V (152 rows) and PosSel (192 rows) ----
  {
    int lr = lane >> 3, lc = (lane & 7) * 8;
    for (int i = wv; i < 19; i += 4) {
      int row = i * 8 + lr;
      int g = gcol(row, c, u0, ncols);
      const bf16* src = kvp + ((size_t)(g * 8 + b)) * 1024 + 512 + h * 64 + lc;
      __builtin_amdgcn_global_load_lds((const AS1 void*)src, (AS3 void*)(Vs + i * 512), 16, 0, 0);
    }
    for (int i = wv; i < 24; i += 4) {
      int p = i * 8 + lr;
      const bf16* src = pos + (size_t)p * 512 + h * 64 + lc;
      __builtin_amdgcn_global_load_lds((const AS1 void*)src, (AS3 void*)(Psl + i * 512), 16, 0, 0);
    }
  }
  // ---- stage Aqu = q + pbu (80 rows), Aqv = q_utt + pbv (64 rows) ----
  for (int id = tid; id < 1152; id += 256) {
    bool isv = id >= 640;
    int lid = isv ? id - 640 : id;
    int m = lid >> 3, ec = lid & 7;
    int qrow;
    if (isv) qrow = 64 + 64 * c + m;
    else qrow = (m < 64) ? (64 + 64 * c + m)
              : (m < 68) ? (4 * c + (m - 64))
              : (m == 68) ? (1088 + c) : 0;
    const uint4 qa = *(const uint4*)(query + ((size_t)(qrow * 8 + b)) * 512 + h * 64 + ec * 8);
    const uint4 ba = *(const uint4*)((isv ? pbv : pbu) + h * 64 + ec * 8);
    uint4 o;
    o.x = pk2(lo16(qa.x) + lo16(ba.x), hi16(qa.x) + hi16(ba.x));
    o.y = pk2(lo16(qa.y) + lo16(ba.y), hi16(qa.y) + hi16(ba.y));
    o.z = pk2(lo16(qa.z) + lo16(ba.z), hi16(qa.z) + hi16(ba.z));
    o.w = pk2(lo16(qa.w) + lo16(ba.w), hi16(qa.w) + hi16(ba.w));
    *(uint4*)((isv ? Aqv : Aqu) + m * 64 + ec * 8) = o;
  }
  __syncthreads();  // s1

  // ---- E GEMM: E[64 x 192] = Aqv @ PosSel^T ----
  float4v eacc[4][3];
  #pragma unroll
  for (int mt = 0; mt < 4; ++mt)
    #pragma unroll
    for (int i = 0; i < 3; ++i) eacc[mt][i] = (float4v){0.f, 0.f, 0.f, 0.f};
  {
    short8v av[4][2];
    #pragma unroll
    for (int mt = 0; mt < 4; ++mt)
      #pragma unroll
      for (int ks = 0; ks < 2; ++ks)
        av[mt][ks] = *(const short8v*)&Aqv[(mt * 16 + l15) * 64 + ks * 32 + quad * 8];
    #pragma unroll
    for (int nti = 0; nti < 3; ++nti) {
      int nt = wv + nti * 4;
      short8v b0 = *(const short8v*)&Psl[(nt * 16 + l15) * 64 + quad * 8];
      short8v b1 = *(const short8v*)&Psl[(nt * 16 + l15) * 64 + 32 + quad * 8];
      #pragma unroll
      for (int mt = 0; mt < 4; ++mt) {
        eacc[mt][nti] = __builtin_amdgcn_mfma_f32_16x16x32_bf16(av[mt][0], b0, eacc[mt][nti], 0, 0, 0);
        eacc[mt][nti] = __builtin_amdgcn_mfma_f32_16x16x32_bf16(av[mt][1], b1, eacc[mt][nti], 0, 0, 0);
      }
    }
  }
  __syncthreads();  // s2: Aqv/Psl dead

  // ---- stage K (over Aqv/Psl head) + scatter E into Eb[m][jl] ----
  {
    int lr = lane >> 3, lc = (lane & 7) * 8;
    for (int i = wv; i < 19; i += 4) {
      int row = i * 8 + lr;
      int g = gcol(row, c, u0, ncols);
      const bf16* src = kvp + ((size_t)(g * 8 + b)) * 1024 + h * 64 + lc;
      __builtin_amdgcn_global_load_lds((const AS1 void*)src, (AS3 void*)(Kt + i * 512), 16, 0, 0);
    }
  }
  #pragma unroll
  for (int nti = 0; nti < 3; ++nti) {
    int p = (wv + nti * 4) * 16 + l15;
    #pragma unroll
    for (int mt = 0; mt < 4; ++mt)
      #pragma unroll
      for (int r = 0; r < 4; ++r) {
        int m = mt * 16 + quad * 4 + r;
        int jl = p - q0 + m;
        if (jl >= 0 && jl < nut) Eb[m * 128 + jl] = __float2bfloat16(eacc[mt][nti][r]);
      }
  }
  __syncthreads();  // s3

  // ---- S GEMM: S[80 x 160] = Aqu @ K^T ----
  const int nnt = (wv < 2) ? 3 : 2;
  float4v sacc[5][3];
  #pragma unroll
  for (int mt = 0; mt < 5; ++mt)
    #pragma unroll
    for (int i = 0; i < 3; ++i) sacc[mt][i] = (float4v){0.f, 0.f, 0.f, 0.f};
  {
    short8v au[5][2];
    #pragma unroll
    for (int mt = 0; mt < 5; ++mt)
      #pragma unroll
      for (int ks = 0; ks < 2; ++ks)
        au[mt][ks] = *(const short8v*)&Aqu[(mt * 16 + l15) * 64 + ks * 32 + quad * 8];
    #pragma unroll
    for (int nti = 0; nti < 3; ++nti) {
      if (nti < nnt) {
        int nt = wv + nti * 4;
        short8v b0 = *(const short8v*)&Kt[(nt * 16 + l15) * 64 + quad * 8];
        short8v b1 = *(const short8v*)&Kt[(nt * 16 + l15) * 64 + 32 + quad * 8];
        #pragma unroll
        for (int mt = 0; mt < 5; ++mt) {
          sacc[mt][nti] = __builtin_amdgcn_mfma_f32_16x16x32_bf16(au[mt][0], b0, sacc[mt][nti], 0, 0, 0);
          sacc[mt][nti] = __builtin_amdgcn_mfma_f32_16x16x32_bf16(au[mt][1], b1, sacc[mt][nti], 0, 0, 0);
        }
      }
    }
  }
  __syncthreads();  // s4: Aqu/Kt dead

  // ---- assembly: + E gather, masks, scale ----
  #pragma unroll
  for (int nti = 0; nti < 3; ++nti) {
    if (nti < nnt) {
      int colv = (wv + nti * 4) * 16 + l15;
      int jl = colv - (c + 4);
      bool cvalid = (colv < ncols) && !(jl >= 0 && jl >= lenlim);
      #pragma unroll
      for (int mt = 0; mt < 5; ++mt)
        #pragma unroll
        for (int r = 0; r < 4; ++r) {
          float s = sacc[mt][nti][r];
          if (cvalid) {
            if (mt < 4 && jl >= 0)
              s += __bfloat162float(Eb[(mt * 16 + quad * 4 + r) * 128 + jl]);
            s *= 0.125f;
          } else s = -1e30f;
          sacc[mt][nti][r] = s;
        }
    }
  }

  // ---- softmax: row max ----
  {
    #pragma unroll
    for (int mt = 0; mt < 5; ++mt)
      #pragma unroll
      for (int r = 0; r < 4; ++r) {
        float v = -3e38f;
        #pragma unroll
        for (int nti = 0; nti < 3; ++nti)
          if (nti < nnt) v = fmaxf(v, sacc[mt][nti][r]);
        v = fmaxf(v, __shfl_xor(v, 1));
        v = fmaxf(v, __shfl_xor(v, 2));
        v = fmaxf(v, __shfl_xor(v, 4));
        v = fmaxf(v, __shfl_xor(v, 8));
        if (l15 == 0) wred[(mt * 16 + quad * 4 + r) * 4 + wv] = v;
      }
  }
  __syncthreads();  // s5
  if (tid < 80)
    rstat[tid] = fmaxf(fmaxf(wred[tid * 4], wred[tid * 4 + 1]),
                       fmaxf(wred[tid * 4 + 2], wred[tid * 4 + 3]));
  __syncthreads();  // s6

  // ---- softmax: exp, write P (bf16, stride 168), row sums ----
  {
    float rmx[5][4], rsum[5][4];
    #pragma unroll
    for (int mt = 0; mt < 5; ++mt)
      #pragma unroll
      for (int r = 0; r < 4; ++r) {
        rmx[mt][r] = rstat[mt * 16 + quad * 4 + r];
        rsum[mt][r] = 0.f;
      }
    #pragma unroll
    for (int nti = 0; nti < 3; ++nti) {
      if (nti < nnt) {
        int colv = (wv + nti * 4) * 16 + l15;
        #pragma unroll
        for (int mt = 0; mt < 5; ++mt)
          #pragma unroll
          for (int r = 0; r < 4; ++r) {
            float p = __expf(sacc[mt][nti][r] - rmx[mt][r]);
            Pp[(mt * 16 + quad * 4 + r) * 168 + colv] = __float2bfloat16(p);
            rsum[mt][r] += p;
          }
      }
    }
    #pragma unroll
    for (int mt = 0; mt < 5; ++mt)
      #pragma unroll
      for (int r = 0; r < 4; ++r) {
        float v = rsum[mt][r];
        v += __shfl_xor(v, 1);
        v += __shfl_xor(v, 2);
        v += __shfl_xor(v, 4);
        v += __shfl_xor(v, 8);
        if (l15 == 0) wred[(mt * 16 + quad * 4 + r) * 4 + wv] = v;
      }
  }
  __syncthreads();  // s7
  if (tid < 80)
    rstat[tid] = 1.f / (wred[tid * 4] + wred[tid * 4 + 1] + wred[tid * 4 + 2] + wred[tid * 4 + 3]);
  __syncthreads();  // s8

  // ---- PV GEMM: O[80 x 64] = P @ V ----
  const int kmax = (ncols + 31) >> 5;
  float4v oacc[5];
  #pragma unroll
  for (int mt = 0; mt < 5; ++mt) oacc[mt] = (float4v){0.f, 0.f, 0.f, 0.f};
  for (int ks = 0; ks < kmax; ++ks) {
    short8v bq;
    #pragma unroll
    for (int j = 0; j < 8; ++j)
      bq[j] = ((const short*)Vs)[(ks * 32 + quad * 8 + j) * 64 + wv * 16 + l15];
    #pragma unroll
    for (int mt = 0; mt < 5; ++mt) {
      short8v af = *(const short8v*)&Pp[(mt * 16 + l15) * 168 + ks * 32 + quad * 8];
      oacc[mt] = __builtin_amdgcn_mfma_f32_16x16x32_bf16(af, bq, oacc[mt], 0, 0, 0);
    }
  }

  // ---- epilogue ----
  #pragma unroll
  for (int mt = 0; mt < 5; ++mt) {
    #pragma unroll
    for (int r = 0; r < 4; ++r) {
      int m = mt * 16 + quad * 4 + r;
      if (m >= 69) continue;
      int qrow = (m < 64) ? (64 + 64 * c + m) : (m < 68) ? (4 * c + (m - 64)) : (1088 + c);
      attn[((size_t)(qrow * 8 + b)) * 512 + h * 64 + wv * 16 + l15] =
          __float2bfloat16(oacc[mt][r] * rstat[m]);
    }
  }
}

__global__ __launch_bounds__(256) void clip_kernel(const bf16* __restrict__ attn,
                                                   void* __restrict__ out,
                                                   const int* __restrict__ flag) {
  const size_t base = (size_t)(RR + UU) * BB * DD;
  int i = blockIdx.x * 256 + threadIdx.x;
  float v = __bfloat162float(attn[base + i]);
  v = fminf(fmaxf(v, -10.f), 10.f);
  if (*flag) ((bf16*)out)[base + i] = __float2bfloat16(v);
  else       ((float*)out)[base + i] = v;
}

static inline int cdiv(int a, int b) { return (a + b - 1) / b; }

extern "C" void kernel_launch(void* const* d_in, const int* in_sizes, int n_in,
                              void* d_out, int out_size, void* d_ws, size_t ws_size,
                              hipStream_t stream) {
  const void* utter = d_in[0];
  const int*  lens  = (const int*)d_in[1];
  const void* rctx  = d_in[2];
  const void* summ  = d_in[3];
  const void* memry = d_in[4];
  // d_in[5] attention_mask: analytic, never read
  const void* pose  = d_in[6];
  const void* W_kv  = d_in[7];
  const void* b_kv  = d_in[8];
  const void* W_q   = d_in[9];
  const void* b_q   = d_in[10];
  const void* W_out = d_in[11];
  const void* b_out = d_in[12];
  const void* W_pos = d_in[13];
  const void* pbu   = d_in[14];
  const void* pbv   = d_in[15];

  const unsigned SZ_RC = RR * BB * DD;       // 262144
  const unsigned SZ_UT = UU * BB * DD;       // 4194304
  const unsigned SZ_SM = SS * BB * DD;       // 65536
  const unsigned SZ_MM = MM * BB * DD;       // 61440
  const unsigned N_XQ  = SZ_RC + SZ_UT + SZ_SM;
  const unsigned N_XKV = SZ_MM + SZ_RC + SZ_UT;
  const unsigned SZ_PS = 191 * DD;           // 97792 (pos rows 896..1086)

  int*  flag = (int*)d_ws;
  bf16* base = (bf16*)((char*)d_ws + 64);
  unsigned off = 0;
  bf16* Xq    = base + off; unsigned o_Xq    = off; off += N_XQ;
  bf16* Xkv   = base + off; unsigned o_Xkv   = off; off += N_XKV;
  bf16* posec = base + off; unsigned o_posec = off; off += 192 * DD;
  bf16* Wq    = base + off; unsigned o_Wq    = off; off += DD * DD;
  bf16* bq    = base + off; unsigned o_bq    = off; off += DD;
  bf16* Wkv   = base + off; unsigned o_Wkv   = off; off += 2 * DD * DD;
  bf16* bkv   = base + off; unsigned o_bkv   = off; off += 2 * DD;
  bf16* Wout  = base + off; unsigned o_Wout  = off; off += DD * DD;
  bf16* bout  = base + off; unsigned o_bout  = off; off += DD;
  bf16* Wpos  = base + off; unsigned o_Wpos  = off; off += DD * DD;
  bf16* pbuc  = base + off; unsigned o_pbu   = off; off += DD;
  bf16* pbvc  = base + off; unsigned o_pbv   = off; off += DD;
  bf16* query = base + off; off += N_XQ;
  bf16* kvp   = base + off; off += N_XKV * 2;
  bf16* pos   = base + off; off += 192 * DD;
  bf16* attn  = base + off; off += N_XQ;

  detect_kernel<<<1, 64, 0, stream>>>(utter, flag);

  // Fused pack: 16 segments
  PackDesc pd;
  const void* srcs[16]  = {rctx, utter, summ, memry, rctx, utter, pose,
                           W_q, b_q, W_kv, b_kv, W_out, b_out, W_pos, pbu, pbv};
  unsigned    soffs[16] = {0, 0, 0, 0, 0, 0, 896u * DD,
                           0, 0, 0, 0, 0, 0, 0, 0, 0};
  unsigned    doffs[16] = {o_Xq, o_Xq + SZ_RC, o_Xq + SZ_RC + SZ_UT,
                           o_Xkv, o_Xkv + SZ_MM, o_Xkv + SZ_MM + SZ_RC,
                           o_posec, o_Wq, o_bq, o_Wkv, o_bkv, o_Wout, o_bout,
                           o_Wpos, o_pbu, o_pbv};
  unsigned    ns[16]    = {SZ_RC, SZ_UT, SZ_SM, SZ_MM, SZ_RC, SZ_UT, SZ_PS,
                           DD * DD, DD, 2 * DD * DD, 2 * DD, DD * DD, DD,
                           DD * DD, DD, DD};
  unsigned cum = 0;
  for (int i = 0; i < 16; ++i) {
    pd.src[i] = srcs[i]; pd.srcoff[i] = soffs[i]; pd.dstoff[i] = doffs[i];
    pd.cum[i] = cum; cum += ns[i] / 8;
  }
  pd.cum[16] = cum;
  int nchunks = (int)cum;
  pack_all<<<dim3(cdiv(nchunks, 256)), dim3(256), 0, stream>>>(pd, base, flag, nchunks);

  dim3 blk(256);
  gemm_mfma<<<dim3(4, 69), blk, 0, stream>>>(Xq, Wq, bq, query, QQ * BB, DD, DD, nullptr);
  gemm_mfma<<<dim3(8, 69), blk, 0, stream>>>(Xkv, Wkv, bkv, kvp, KVL * BB, 2 * DD, DD, nullptr);
  gemm_mfma<<<dim3(4, 2), blk, 0, stream>>>(posec, Wpos, nullptr, pos, 191, DD, DD, nullptr);
  attn_chunk<<<dim3(1024), blk, 0, stream>>>(query, kvp, pos, pbuc, pbvc, lens, attn);
  gemm_mfma<<<dim3(4, 68), blk, 0, stream>>>(attn, Wout, bout, d_out, (RR + UU) * BB, DD, DD, flag);
  clip_kernel<<<dim3((SS * BB * DD) / 256), blk, 0, stream>>>(attn, d_out, flag);
}

// Round 5
// 246.790 us; speedup vs baseline: 6.1151x; 1.1413x over previous
//
#include <hip/hip_runtime.h>
#include <hip/hip_bf16.h>

typedef __hip_bfloat16 bf16;
typedef __attribute__((ext_vector_type(8))) short short8v;   // 8 bf16 (4 VGPRs)
typedef __attribute__((ext_vector_type(4))) float float4v;   // MFMA C/D frag

// Problem constants
#define UU 1024
#define BB 8
#define DD 512
#define HH 8
#define HD 64
#define RR 64
#define SS 16
#define MM 15
#define QQ 1104   // R + U + S
#define KVL 1103  // M + R + U
#define PEL 2047
#define NU 1536   // fused QKV output width
#define MU 8952   // union rows (15+64+1024+16)*8

#define AS1 __attribute__((address_space(1)))
#define AS3 __attribute__((address_space(3)))

// ---- dtype detection: is the float data bf16 (flag=1) or fp32 (flag=0)? ----
__global__ void detect_kernel(const void* probe, int* flag) {
  const unsigned short* p = (const unsigned short*)probe;
  int tid = threadIdx.x;
  int big = 0;
  for (int i = tid; i < 4096; i += 64) {
    int e = (p[i] >> 7) & 0xFF;
    if (e >= 137) big++;
  }
  #pragma unroll
  for (int off = 32; off; off >>= 1) big += __shfl_down(big, off);
  if (tid == 0) *flag = (big < 16) ? 1 : 0;
}

// ---- fused canonicalization of all float inputs into bf16 workspace ----
struct PackDesc {
  const void* src[16];
  unsigned int srcoff[16];
  unsigned int dstoff[16];
  unsigned int cum[17];   // cumulative 8-element chunks
};

__device__ __forceinline__ float lo16(unsigned u) { return __uint_as_float(u << 16); }
__device__ __forceinline__ float hi16(unsigned u) { return __uint_as_float(u & 0xffff0000u); }
__device__ __forceinline__ unsigned pk2(float a, float b) {
  unsigned short x = __builtin_bit_cast(unsigned short, __float2bfloat16(a));
  unsigned short y = __builtin_bit_cast(unsigned short, __float2bfloat16(b));
  return (unsigned)x | ((unsigned)y << 16);
}

__global__ __launch_bounds__(256) void pack_all(PackDesc d, bf16* base,
                                                const int* __restrict__ flag,
                                                int nchunks) {
  int g = blockIdx.x * 256 + threadIdx.x;
  if (g >= nchunks) return;
  int s = 0;
  #pragma unroll
  for (int i = 1; i < 17; ++i) s += (g >= d.cum[i]) ? 1 : 0;
  unsigned local = (g - d.cum[s]) * 8u;
  bf16* dst = base + d.dstoff[s] + local;
  if (*flag) {
    const uint4 v = *(const uint4*)((const bf16*)d.src[s] + d.srcoff[s] + local);
    *(uint4*)dst = v;
  } else {
    const float* fp = (const float*)d.src[s] + d.srcoff[s] + local;
    uint4 o;
    o.x = pk2(fp[0], fp[1]);
    o.y = pk2(fp[2], fp[3]);
    o.z = pk2(fp[4], fp[5]);
    o.w = pk2(fp[6], fp[7]);
    *(uint4*)dst = o;
  }
}

// ---- MFMA GEMM with XOR-swizzled LDS: out[m,n] = X[m,:]·W[n,:] (+bias) ----
// 16-B block b of row r stored at slot (b ^ (r&7)); staging permutes the
// per-lane SOURCE address (global_load_lds dest stays wave-contiguous).
__global__ __launch_bounds__(256) void gemm_mfma(
    const bf16* __restrict__ X, const bf16* __restrict__ W,
    const bf16* __restrict__ bias, void* __restrict__ out,
    int M, int N, int K, const int* __restrict__ outf) {
  __shared__ bf16 As[128 * 64];
  __shared__ bf16 Bs[128 * 64];
  const int tid = threadIdx.x;
  const int lane = tid & 63, wv = tid >> 6;
  const int wr = wv >> 1, wc = wv & 1;
  const int bm = blockIdx.y * 128, bn = blockIdx.x * 128;
  const int lrow = lane >> 3;              // 0..7 row within staged group
  const int sb = (lane & 7) ^ lrow;        // swizzled source 16B-block

  float4v acc[4][4] = {};

  for (int kb = 0; kb < K; kb += 64) {
    #pragma unroll
    for (int i = 0; i < 4; ++i) {
      int r = wv * 32 + i * 8 + lrow;
      int gm = bm + r; if (gm > M - 1) gm = M - 1;
      const bf16* src = X + (size_t)gm * K + kb + sb * 8;
      __builtin_amdgcn_global_load_lds((const AS1 void*)src,
                                       (AS3 void*)&As[(wv * 32 + i * 8) * 64], 16, 0, 0);
    }
    #pragma unroll
    for (int i = 0; i < 4; ++i) {
      int r = wv * 32 + i * 8 + lrow;
      const bf16* src = W + (size_t)(bn + r) * K + kb + sb * 8;
      __builtin_amdgcn_global_load_lds((const AS1 void*)src,
                                       (AS3 void*)&Bs[(wv * 32 + i * 8) * 64], 16, 0, 0);
    }
    __syncthreads();
    const int quad = lane >> 4, l15 = lane & 15, key = l15 & 7;
    #pragma unroll
    for (int ki = 0; ki < 2; ++ki) {
      const int blk = (ki * 4 + quad) ^ key;
      short8v a[4], bq[4];
      #pragma unroll
      for (int t = 0; t < 4; ++t)
        a[t] = *(const short8v*)&As[(wr * 64 + t * 16 + l15) * 64 + blk * 8];
      #pragma unroll
      for (int t = 0; t < 4; ++t)
        bq[t] = *(const short8v*)&Bs[(wc * 64 + t * 16 + l15) * 64 + blk * 8];
      #pragma unroll
      for (int mt = 0; mt < 4; ++mt)
        #pragma unroll
        for (int nt = 0; nt < 4; ++nt)
          acc[mt][nt] = __builtin_amdgcn_mfma_f32_16x16x32_bf16(
              a[mt], bq[nt], acc[mt][nt], 0, 0, 0);
    }
    __syncthreads();
  }

  const bool as_bf16 = (outf == nullptr) ? true : (*outf != 0);
  const int quad = lane >> 4, cn = lane & 15;
  #pragma unroll
  for (int mt = 0; mt < 4; ++mt) {
    #pragma unroll
    for (int r = 0; r < 4; ++r) {
      int gm = bm + wr * 64 + mt * 16 + quad * 4 + r;
      if (gm >= M) continue;
      #pragma unroll
      for (int nt = 0; nt < 4; ++nt) {
        int gn = bn + wc * 64 + nt * 16 + cn;
        float v = acc[mt][nt][r];
        if (bias) v += __bfloat162float(bias[gn]);
        size_t o = (size_t)gm * N + gn;
        if (as_bf16) ((bf16*)out)[o] = __float2bfloat16(v);
        else         ((float*)out)[o] = v;
      }
    }
  }
}

// ---- MFMA chunk attention: one block per (c, b, h) ----
__device__ __forceinline__ int gcol(int row, int c, int u0, int ncols) {
  if (row < c) return row;
  if (row < c + 4) return 15 + 4 * c + (row - c);
  if (row < ncols) return 79 + u0 + (row - c - 4);
  return 0;
}

__global__ __launch_bounds__(256, 2) void attn_chunk(
    const bf16* __restrict__ qkv, const bf16* __restrict__ pos,
    const bf16* __restrict__ pbu, const bf16* __restrict__ pbv,
    const int* __restrict__ lengths, bf16* __restrict__ attn) {
  __shared__ char lds[65536];
  bf16* Vs   = (bf16*)(lds);           // [152][64]  (k>>3)-swizzled, whole life
  bf16* Aqu  = (bf16*)(lds + 19456);   // [80][64]   row&7-swizzled, whole life
  bf16* Kt   = (bf16*)(lds + 29696);   // [152][64]  row&7-swizzled, phase B
  bf16* Aqv  = (bf16*)(lds + 32768);   // [64][64]   row&7-swizzled, phase A
  bf16* Psl  = (bf16*)(lds + 40960);   // [192][64]  row&7-swizzled, phase A
  bf16* Eb   = (bf16*)(lds + 49152);   // [64][128]  bank-swizzled, phase B
  bf16* Pp   = (bf16*)(lds + 19456);   // [80][168]  softmax phase (over Aqu/Kt)
  float* wred  = (float*)(lds + 46336); // [80][4]   (over Kt tail, dead then)
  float* rstat = (float*)(lds + 47616); // [80]

  const int idx = blockIdx.x;
  const int h = idx & 7, b = (idx >> 3) & 7, c = idx >> 6;
  const int u0 = c ? (c - 1) * 64 : 0;
  const int nut = c ? 128 : 64;
  const int ncols = c + 4 + nut;
  const int q0 = c ? 63 : 127;     // pos row p = q0 - m + jl
  const int tid = threadIdx.x, lane = tid & 63, wv = tid >> 6;
  const int quad = lane >> 4, l15 = lane & 15, key = l15 & 7;
  const int lenlim = lengths[b] - u0;

  // ---- stage V (152 rows, (k>>3)&7-swizzle) and PosSel (192 rows) ----
  {
    int lr = lane >> 3;
    int sbr = (lane & 7) ^ lr;   // row&7 swizzle (row ≡ lr mod 8)
    for (int i = wv; i < 19; i += 4) {
      int row = i * 8 + lr;
      int g = gcol(row, c, u0, ncols);
      int sbv = (lane & 7) ^ (i & 7);  // key = (k>>3)&7 = i&7 for this row
      const bf16* src = qkv + ((size_t)(g * 8 + b)) * NU + 1024 + h * 64 + sbv * 8;
      __builtin_amdgcn_global_load_lds((const AS1 void*)src, (AS3 void*)(Vs + i * 512), 16, 0, 0);
    }
    for (int i = wv; i < 24; i += 4) {
      int p = i * 8 + lr;
      const bf16* src = pos + (size_t)p * 512 + h * 64 + sbr * 8;
      __builtin_amdgcn_global_load_lds((const AS1 void*)src, (AS3 void*)(Psl + i * 512), 16, 0, 0);
    }
  }
  // ---- stage Aqu = q + pbu (80 rows), Aqv = q_utt + pbv (64 rows) ----
  for (int id = tid; id < 1152; id += 256) {
    bool isv = id >= 640;
    int lid = isv ? id - 640 : id;
    int m = lid >> 3, ec = lid & 7;
    int qrow;
    if (isv) qrow = 64 + 64 * c + m;
    else qrow = (m < 64) ? (64 + 64 * c + m)
              : (m < 68) ? (4 * c + (m - 64))
              : (m == 68) ? (1088 + c) : 0;
    // q lives in fused QKV at union row = qrow + 15, cols [0,512)
    const uint4 qa = *(const uint4*)(qkv + ((size_t)((qrow + 15) * 8 + b)) * NU + h * 64 + ec * 8);
    const uint4 ba = *(const uint4*)((isv ? pbv : pbu) + h * 64 + ec * 8);
    uint4 o;
    o.x = pk2(lo16(qa.x) + lo16(ba.x), hi16(qa.x) + hi16(ba.x));
    o.y = pk2(lo16(qa.y) + lo16(ba.y), hi16(qa.y) + hi16(ba.y));
    o.z = pk2(lo16(qa.z) + lo16(ba.z), hi16(qa.z) + hi16(ba.z));
    o.w = pk2(lo16(qa.w) + lo16(ba.w), hi16(qa.w) + hi16(ba.w));
    *(uint4*)((isv ? Aqv : Aqu) + m * 64 + (ec ^ (m & 7)) * 8) = o;
  }
  __syncthreads();  // s1

  // ---- E GEMM: E[64 x 192] = Aqv @ PosSel^T ----
  float4v eacc[4][3];
  #pragma unroll
  for (int mt = 0; mt < 4; ++mt)
    #pragma unroll
    for (int i = 0; i < 3; ++i) eacc[mt][i] = (float4v){0.f, 0.f, 0.f, 0.f};
  {
    short8v av[4][2];
    #pragma unroll
    for (int mt = 0; mt < 4; ++mt)
      #pragma unroll
      for (int ks = 0; ks < 2; ++ks)
        av[mt][ks] = *(const short8v*)&Aqv[(mt * 16 + l15) * 64 + ((ks * 4 + quad) ^ key) * 8];
    #pragma unroll
    for (int nti = 0; nti < 3; ++nti) {
      int nt = wv + nti * 4;
      short8v b0 = *(const short8v*)&Psl[(nt * 16 + l15) * 64 + (quad ^ key) * 8];
      short8v b1 = *(const short8v*)&Psl[(nt * 16 + l15) * 64 + ((4 + quad) ^ key) * 8];
      #pragma unroll
      for (int mt = 0; mt < 4; ++mt) {
        eacc[mt][nti] = __builtin_amdgcn_mfma_f32_16x16x32_bf16(av[mt][0], b0, eacc[mt][nti], 0, 0, 0);
        eacc[mt][nti] = __builtin_amdgcn_mfma_f32_16x16x32_bf16(av[mt][1], b1, eacc[mt][nti], 0, 0, 0);
      }
    }
  }
  __syncthreads();  // s2: Aqv/Psl dead

  // ---- stage K (row&7-swizzle) + scatter E into Eb (bank-swizzled) ----
  {
    int lr = lane >> 3, sbr = (lane & 7) ^ lr;
    for (int i = wv; i < 19; i += 4) {
      int row = i * 8 + lr;
      int g = gcol(row, c, u0, ncols);
      const bf16* src = qkv + ((size_t)(g * 8 + b)) * NU + 512 + h * 64 + sbr * 8;
      __builtin_amdgcn_global_load_lds((const AS1 void*)src, (AS3 void*)(Kt + i * 512), 16, 0, 0);
    }
  }
  #pragma unroll
  for (int nti = 0; nti < 3; ++nti) {
    int p = (wv + nti * 4) * 16 + l15;
    #pragma unroll
    for (int mt = 0; mt < 4; ++mt)
      #pragma unroll
      for (int r = 0; r < 4; ++r) {
        int m = mt * 16 + quad * 4 + r;
        int jl = p - q0 + m;
        if (jl >= 0 && jl < nut)
          Eb[m * 128 + (jl ^ (((m >> 2) & 7) << 4))] = __float2bfloat16(eacc[mt][nti][r]);
      }
  }
  __syncthreads();  // s3

  // ---- S GEMM: S[80 x 160] = Aqu @ K^T ----
  const int nnt = (wv < 2) ? 3 : 2;
  float4v sacc[5][3];
  #pragma unroll
  for (int mt = 0; mt < 5; ++mt)
    #pragma unroll
    for (int i = 0; i < 3; ++i) sacc[mt][i] = (float4v){0.f, 0.f, 0.f, 0.f};
  {
    short8v au[5][2];
    #pragma unroll
    for (int mt = 0; mt < 5; ++mt)
      #pragma unroll
      for (int ks = 0; ks < 2; ++ks)
        au[mt][ks] = *(const short8v*)&Aqu[(mt * 16 + l15) * 64 + ((ks * 4 + quad) ^ key) * 8];
    #pragma unroll
    for (int nti = 0; nti < 3; ++nti) {
      if (nti < nnt) {
        int nt = wv + nti * 4;
        short8v b0 = *(const short8v*)&Kt[(nt * 16 + l15) * 64 + (quad ^ key) * 8];
        short8v b1 = *(const short8v*)&Kt[(nt * 16 + l15) * 64 + ((4 + quad) ^ key) * 8];
        #pragma unroll
        for (int mt = 0; mt < 5; ++mt) {
          sacc[mt][nti] = __builtin_amdgcn_mfma_f32_16x16x32_bf16(au[mt][0], b0, sacc[mt][nti], 0, 0, 0);
          sacc[mt][nti] = __builtin_amdgcn_mfma_f32_16x16x32_bf16(au[mt][1], b1, sacc[mt][nti], 0, 0, 0);
        }
      }
    }
  }
  __syncthreads();  // s4: Aqu/Kt dead

  // ---- assembly: + E gather, masks, scale ----
  #pragma unroll
  for (int nti = 0; nti < 3; ++nti) {
    if (nti < nnt) {
      int colv = (wv + nti * 4) * 16 + l15;
      int jl = colv - (c + 4);
      bool cvalid = (colv < ncols) && !(jl >= 0 && jl >= lenlim);
      #pragma unroll
      for (int mt = 0; mt < 5; ++mt)
        #pragma unroll
        for (int r = 0; r < 4; ++r) {
          float s = sacc[mt][nti][r];
          if (cvalid) {
            if (mt < 4 && jl >= 0) {
              int m = mt * 16 + quad * 4 + r;
              s += __bfloat162float(Eb[m * 128 + (jl ^ (((m >> 2) & 7) << 4))]);
            }
            s *= 0.125f;
          } else s = -1e30f;
          sacc[mt][nti][r] = s;
        }
    }
  }

  // ---- softmax: row max ----
  {
    #pragma unroll
    for (int mt = 0; mt < 5; ++mt)
      #pragma unroll
      for (int r = 0; r < 4; ++r) {
        float v = -3e38f;
        #pragma unroll
        for (int nti = 0; nti < 3; ++nti)
          if (nti < nnt) v = fmaxf(v, sacc[mt][nti][r]);
        v = fmaxf(v, __shfl_xor(v, 1));
        v = fmaxf(v, __shfl_xor(v, 2));
        v = fmaxf(v, __shfl_xor(v, 4));
        v = fmaxf(v, __shfl_xor(v, 8));
        if (l15 == 0) wred[(mt * 16 + quad * 4 + r) * 4 + wv] = v;
      }
  }
  __syncthreads();  // s5
  if (tid < 80)
    rstat[tid] = fmaxf(fmaxf(wred[tid * 4], wred[tid * 4 + 1]),
                       fmaxf(wred[tid * 4 + 2], wred[tid * 4 + 3]));
  __syncthreads();  // s6

  // ---- softmax: exp, write P (bf16, stride 168), row sums ----
  {
    float rmx[5][4], rsum[5][4];
    #pragma unroll
    for (int mt = 0; mt < 5; ++mt)
      #pragma unroll
      for (int r = 0; r < 4; ++r) {
        rmx[mt][r] = rstat[mt * 16 + quad * 4 + r];
        rsum[mt][r] = 0.f;
      }
    #pragma unroll
    for (int nti = 0; nti < 3; ++nti) {
      if (nti < nnt) {
        int colv = (wv + nti * 4) * 16 + l15;
        #pragma unroll
        for (int mt = 0; mt < 5; ++mt)
          #pragma unroll
          for (int r = 0; r < 4; ++r) {
            float p = __expf(sacc[mt][nti][r] - rmx[mt][r]);
            Pp[(mt * 16 + quad * 4 + r) * 168 + colv] = __float2bfloat16(p);
            rsum[mt][r] += p;
          }
      }
    }
    #pragma unroll
    for (int mt = 0; mt < 5; ++mt)
      #pragma unroll
      for (int r = 0; r < 4; ++r) {
        float v = rsum[mt][r];
        v += __shfl_xor(v, 1);
        v += __shfl_xor(v, 2);
        v += __shfl_xor(v, 4);
        v += __shfl_xor(v, 8);
        if (l15 == 0) wred[(mt * 16 + quad * 4 + r) * 4 + wv] = v;
      }
  }
  __syncthreads();  // s7
  if (tid < 80)
    rstat[tid] = 1.f / (wred[tid * 4] + wred[tid * 4 + 1] + wred[tid * 4 + 2] + wred[tid * 4 + 3]);
  __syncthreads();  // s8

  // ---- PV GEMM: O[80 x 64] = P @ V (Vs reads swizzled by (k>>3)&7) ----
  const int kmax = (ncols + 31) >> 5;
  float4v oacc[5];
  #pragma unroll
  for (int mt = 0; mt < 5; ++mt) oacc[mt] = (float4v){0.f, 0.f, 0.f, 0.f};
  const int ehi = (wv * 16 + l15) >> 3, elo = l15 & 7;
  for (int ks = 0; ks < kmax; ++ks) {
    short8v bq;
    const int blk = ehi ^ ((ks * 4 + quad) & 7);
    #pragma unroll
    for (int j = 0; j < 8; ++j)
      bq[j] = ((const short*)Vs)[(ks * 32 + quad * 8 + j) * 64 + blk * 8 + elo];
    #pragma unroll
    for (int mt = 0; mt < 5; ++mt) {
      short8v af = *(const short8v*)&Pp[(mt * 16 + l15) * 168 + ks * 32 + quad * 8];
      oacc[mt] = __builtin_amdgcn_mfma_f32_16x16x32_bf16(af, bq, oacc[mt], 0, 0, 0);
    }
  }

  // ---- epilogue ----
  #pragma unroll
  for (int mt = 0; mt < 5; ++mt) {
    #pragma unroll
    for (int r = 0; r < 4; ++r) {
      int m = mt * 16 + quad * 4 + r;
      if (m >= 69) continue;
      int qrow = (m < 64) ? (64 + 64 * c + m) : (m < 68) ? (4 * c + (m - 64)) : (1088 + c);
      attn[((size_t)(qrow * 8 + b)) * 512 + h * 64 + wv * 16 + l15] =
          __float2bfloat16(oacc[mt][r] * rstat[m]);
    }
  }
}

__global__ __launch_bounds__(256) void clip_kernel(const bf16* __restrict__ attn,
                                                   void* __restrict__ out,
                                                   const int* __restrict__ flag) {
  const size_t base = (size_t)(RR + UU) * BB * DD;
  int i = blockIdx.x * 256 + threadIdx.x;
  float v = __bfloat162float(attn[base + i]);
  v = fminf(fmaxf(v, -10.f), 10.f);
  if (*flag) ((bf16*)out)[base + i] = __float2bfloat16(v);
  else       ((float*)out)[base + i] = v;
}

static inline int cdiv(int a, int b) { return (a + b - 1) / b; }

extern "C" void kernel_launch(void* const* d_in, const int* in_sizes, int n_in,
                              void* d_out, int out_size, void* d_ws, size_t ws_size,
                              hipStream_t stream) {
  const void* utter = d_in[0];
  const int*  lens  = (const int*)d_in[1];
  const void* rctx  = d_in[2];
  const void* summ  = d_in[3];
  const void* memry = d_in[4];
  // d_in[5] attention_mask: analytic, never read
  const void* pose  = d_in[6];
  const void* W_kv  = d_in[7];
  const void* b_kv  = d_in[8];
  const void* W_q   = d_in[9];
  const void* b_q   = d_in[10];
  const void* W_out = d_in[11];
  const void* b_out = d_in[12];
  const void* W_pos = d_in[13];
  const void* pbu   = d_in[14];
  const void* pbv   = d_in[15];

  const unsigned SZ_MM = MM * BB * DD;   // 61440
  const unsigned SZ_RC = RR * BB * DD;   // 262144
  const unsigned SZ_UT = UU * BB * DD;   // 4194304
  const unsigned SZ_SM = SS * BB * DD;   // 65536
  const unsigned N_XU  = SZ_MM + SZ_RC + SZ_UT + SZ_SM;  // 4583424
  const unsigned SZ_PS = 191 * DD;       // 97792

  int*  flag = (int*)d_ws;
  bf16* base = (bf16*)((char*)d_ws + 64);
  unsigned off = 0;
  bf16* XU    = base + off; unsigned o_XU    = off; off += N_XU;
  bf16* posec = base + off; unsigned o_posec = off; off += 192 * DD;
  bf16* Wcat  = base + off; unsigned o_Wcat  = off; off += (unsigned)NU * DD;
  bf16* bcat  = base + off; unsigned o_bcat  = off; off += NU;
  bf16* Wout  = base + off; unsigned o_Wout  = off; off += DD * DD;
  bf16* bout  = base + off; unsigned o_bout  = off; off += DD;
  bf16* Wpos  = base + off; unsigned o_Wpos  = off; off += DD * DD;
  bf16* pbuc  = base + off; unsigned o_pbu   = off; off += DD;
  bf16* pbvc  = base + off; unsigned o_pbv   = off; off += DD;
  bf16* qkv   = base + off; off += (unsigned)(MU + 8) * NU;  // 8952 x 1536
  bf16* pos   = base + off; off += 192 * DD;
  bf16* attn  = base + off; off += QQ * BB * DD;

  detect_kernel<<<1, 64, 0, stream>>>(utter, flag);

  // Fused pack: 14 segments (union X = [mem | rc | utt | summ])
  PackDesc pd;
  const void* srcs[14]  = {memry, rctx, utter, summ, pose,
                           W_q, W_kv, b_q, b_kv, W_out, b_out, W_pos, pbu, pbv};
  unsigned    soffs[14] = {0, 0, 0, 0, 896u * DD, 0, 0, 0, 0, 0, 0, 0, 0, 0};
  unsigned    doffs[14] = {o_XU, o_XU + SZ_MM, o_XU + SZ_MM + SZ_RC,
                           o_XU + SZ_MM + SZ_RC + SZ_UT, o_posec,
                           o_Wcat, o_Wcat + DD * DD, o_bcat, o_bcat + DD,
                           o_Wout, o_bout, o_Wpos, o_pbu, o_pbv};
  unsigned    ns[14]    = {SZ_MM, SZ_RC, SZ_UT, SZ_SM, SZ_PS,
                           DD * DD, 2 * DD * DD, DD, 2 * DD,
                           DD * DD, DD, DD * DD, DD, DD};
  unsigned cum = 0;
  for (int i = 0; i < 14; ++i) {
    pd.src[i] = srcs[i]; pd.srcoff[i] = soffs[i]; pd.dstoff[i] = doffs[i];
    pd.cum[i] = cum; cum += ns[i] / 8;
  }
  pd.src[14] = pbv; pd.srcoff[14] = 0; pd.dstoff[14] = o_pbv;
  pd.src[15] = pbv; pd.srcoff[15] = 0; pd.dstoff[15] = o_pbv;
  pd.cum[14] = cum; pd.cum[15] = cum; pd.cum[16] = cum;
  int nchunks = (int)cum;
  pack_all<<<dim3(cdiv(nchunks, 256)), dim3(256), 0, stream>>>(pd, base, flag, nchunks);

  dim3 blk(256);
  // fused QKV: XU(8952 x 512) @ [W_q;W_kv]^T -> (8952 x 1536)
  gemm_mfma<<<dim3(12, 70), blk, 0, stream>>>(XU, Wcat, bcat, qkv, MU, NU, DD, nullptr);
  // pos: posec(191 x 512) @ W_pos^T -> (191 x 512)
  gemm_mfma<<<dim3(4, 2), blk, 0, stream>>>(posec, Wpos, nullptr, pos, 191, DD, DD, nullptr);
  // attention: one block per (c, b, h)
  attn_chunk<<<dim3(1024), blk, 0, stream>>>(qkv, pos, pbuc, pbvc, lens, attn);
  // out_ru = attn[:1088] @ W_out^T + b_out
  gemm_mfma<<<dim3(4, 68), blk, 0, stream>>>(attn, Wout, bout, d_out, (RR + UU) * BB, DD, DD, flag);
  // out_mem = clip(attn[1088:], -10, 10)
  clip_kernel<<<dim3((SS * BB * DD) / 256), blk, 0, stream>>>(attn, d_out, flag);
}

// Round 6
// 220.817 us; speedup vs baseline: 6.8344x; 1.1176x over previous
//
#include <hip/hip_runtime.h>
#include <hip/hip_bf16.h>

typedef __hip_bfloat16 bf16;
typedef __attribute__((ext_vector_type(8))) short short8v;   // 8 bf16 (4 VGPRs)
typedef __attribute__((ext_vector_type(4))) float float4v;   // MFMA C/D frag

// Problem constants
#define UU 1024
#define BB 8
#define DD 512
#define HH 8
#define HD 64
#define RR 64
#define SS 16
#define MM 15
#define QQ 1104   // R + U + S
#define KVL 1103  // M + R + U
#define PEL 2047
#define NU 1536   // fused QKV output width
#define MU 8952   // union rows (15+64+1024+16)*8

#define AS1 __attribute__((address_space(1)))
#define AS3 __attribute__((address_space(3)))

__device__ __forceinline__ float lo16(unsigned u) { return __uint_as_float(u << 16); }
__device__ __forceinline__ float hi16(unsigned u) { return __uint_as_float(u & 0xffff0000u); }
__device__ __forceinline__ unsigned pk2(float a, float b) {
  unsigned short x = __builtin_bit_cast(unsigned short, __float2bfloat16(a));
  unsigned short y = __builtin_bit_cast(unsigned short, __float2bfloat16(b));
  return (unsigned)x | ((unsigned)y << 16);
}

// ---- fused canonicalization + in-block dtype detection ----
struct PackDesc {
  const void* src[16];
  unsigned int srcoff[16];
  unsigned int dstoff[16];
  unsigned int cum[17];   // cumulative 8-element chunks
};

__global__ __launch_bounds__(256) void pack_all(PackDesc d, bf16* base,
                                                const void* __restrict__ probe,
                                                int* __restrict__ flagout,
                                                int nchunks) {
  // dtype detection: bf16 normals have exp<=~132; fp32-reinterpreted halves
  // show ~46% with exp>=137. Every block derives the same flag (parallel, cheap).
  __shared__ int wsum[4];
  const unsigned short* p = (const unsigned short*)probe;
  int big = 0;
  for (int i = threadIdx.x; i < 4096; i += 256)
    big += (((p[i] >> 7) & 0xFF) >= 137) ? 1 : 0;
  #pragma unroll
  for (int off = 32; off; off >>= 1) big += __shfl_down(big, off);
  if ((threadIdx.x & 63) == 0) wsum[threadIdx.x >> 6] = big;
  __syncthreads();
  const int flag = (wsum[0] + wsum[1] + wsum[2] + wsum[3] < 16) ? 1 : 0;
  if (threadIdx.x == 0 && blockIdx.x == 0) *flagout = flag;

  int g = blockIdx.x * 256 + threadIdx.x;
  if (g >= nchunks) return;
  int s = 0;
  #pragma unroll
  for (int i = 1; i < 17; ++i) s += (g >= d.cum[i]) ? 1 : 0;
  unsigned local = (g - d.cum[s]) * 8u;
  bf16* dst = base + d.dstoff[s] + local;
  if (flag) {
    const uint4 v = *(const uint4*)((const bf16*)d.src[s] + d.srcoff[s] + local);
    *(uint4*)dst = v;
  } else {
    const float* fp = (const float*)d.src[s] + d.srcoff[s] + local;
    uint4 o;
    o.x = pk2(fp[0], fp[1]);
    o.y = pk2(fp[2], fp[3]);
    o.z = pk2(fp[4], fp[5]);
    o.w = pk2(fp[6], fp[7]);
    *(uint4*)dst = o;
  }
}

// ---- MFMA GEMM, BK=128, XOR-swizzled LDS (16-B block b of row r at b^(r&15)).
// gemm_dual runs two GEMMs in one dispatch: blockIdx.y < ysplit -> g0 tile
// (x,y); else g1 tiles linearized over the remaining row(s).
struct GemmP {
  const bf16* X; const bf16* W; const bf16* bias; void* out;
  int M, N, K; const int* outf;
};

__global__ __launch_bounds__(256) void gemm_dual(GemmP g0, GemmP g1, int ysplit) {
  __shared__ bf16 As[128 * 128];
  __shared__ bf16 Bs[128 * 128];
  GemmP g; int bm, bn;
  if ((int)blockIdx.y < ysplit) {
    g = g0; bm = blockIdx.y * 128; bn = blockIdx.x * 128;
  } else {
    g = g1;
    int nt = g1.N >> 7;
    int bi = ((int)blockIdx.y - ysplit) * gridDim.x + blockIdx.x;
    if (bi >= ((g1.M + 127) >> 7) * nt) return;
    bm = (bi / nt) * 128; bn = (bi % nt) * 128;
  }
  const int tid = threadIdx.x;
  const int lane = tid & 63, wv = tid >> 6;
  const int wr = wv >> 1, wc = wv & 1;
  const int l4 = lane >> 4;            // row within 4-row staging group
  const int lb = lane & 15;            // 16B block within 256B row
  const int quad = lane >> 4, l15 = lane & 15;

  float4v acc[4][4] = {};

  for (int kb = 0; kb < g.K; kb += 128) {
    #pragma unroll
    for (int i = 0; i < 8; ++i) {
      int r = wv * 32 + i * 4 + l4;
      int gm = bm + r; if (gm > g.M - 1) gm = g.M - 1;
      const bf16* src = g.X + (size_t)gm * g.K + kb + ((lb ^ (r & 15)) * 8);
      __builtin_amdgcn_global_load_lds((const AS1 void*)src,
                                       (AS3 void*)&As[(wv * 32 + i * 4) * 128], 16, 0, 0);
    }
    #pragma unroll
    for (int i = 0; i < 8; ++i) {
      int r = wv * 32 + i * 4 + l4;
      int gn = bn + r; if (gn > g.N - 1) gn = g.N - 1;
      const bf16* src = g.W + (size_t)gn * g.K + kb + ((lb ^ (r & 15)) * 8);
      __builtin_amdgcn_global_load_lds((const AS1 void*)src,
                                       (AS3 void*)&Bs[(wv * 32 + i * 4) * 128], 16, 0, 0);
    }
    __syncthreads();
    #pragma unroll
    for (int ki = 0; ki < 4; ++ki) {
      const int gblk = ki * 4 + quad;
      const int slot = (gblk ^ l15) * 8;   // (r&15) == l15 for all frag rows
      short8v a[4], bq[4];
      #pragma unroll
      for (int t = 0; t < 4; ++t) {
        a[t]  = *(const short8v*)&As[(wr * 64 + t * 16 + l15) * 128 + slot];
        bq[t] = *(const short8v*)&Bs[(wc * 64 + t * 16 + l15) * 128 + slot];
      }
      #pragma unroll
      for (int mt = 0; mt < 4; ++mt)
        #pragma unroll
        for (int nt = 0; nt < 4; ++nt)
          acc[mt][nt] = __builtin_amdgcn_mfma_f32_16x16x32_bf16(
              a[mt], bq[nt], acc[mt][nt], 0, 0, 0);
    }
    __syncthreads();
  }

  const bool as_bf16 = (g.outf == nullptr) ? true : (*g.outf != 0);
  #pragma unroll
  for (int mt = 0; mt < 4; ++mt) {
    #pragma unroll
    for (int r = 0; r < 4; ++r) {
      int gm = bm + wr * 64 + mt * 16 + quad * 4 + r;
      if (gm >= g.M) continue;
      #pragma unroll
      for (int nt = 0; nt < 4; ++nt) {
        int gn = bn + wc * 64 + nt * 16 + l15;
        float v = acc[mt][nt][r];
        if (g.bias) v += __bfloat162float(g.bias[gn]);
        size_t o = (size_t)gm * g.N + gn;
        if (as_bf16) ((bf16*)g.out)[o] = __float2bfloat16(v);
        else         ((float*)g.out)[o] = v;
      }
    }
  }
}

// ---- MFMA chunk attention: one block per (c, b, h) ----
__device__ __forceinline__ int gcol(int row, int c, int u0, int ncols) {
  if (row < c) return row;
  if (row < c + 4) return 15 + 4 * c + (row - c);
  if (row < ncols) return 79 + u0 + (row - c - 4);
  return 0;
}

__global__ __launch_bounds__(256, 2) void attn_chunk(
    const bf16* __restrict__ qkv, const bf16* __restrict__ pos,
    const bf16* __restrict__ pbu, const bf16* __restrict__ pbv,
    const int* __restrict__ lengths, bf16* __restrict__ attn,
    const int* __restrict__ flag, void* __restrict__ dout) {
  __shared__ char lds[65536];
  bf16* Vs   = (bf16*)(lds);           // [152][64]  (k>>3)-swizzled, whole life
  bf16* Aqu  = (bf16*)(lds + 19456);   // [80][64]   row&7-swizzled, whole life
  bf16* Kt   = (bf16*)(lds + 29696);   // [152][64]  row&7-swizzled, phase B
  bf16* Aqv  = (bf16*)(lds + 32768);   // [64][64]   row&7-swizzled, phase A
  bf16* Psl  = (bf16*)(lds + 40960);   // [192][64]  row&7-swizzled, phase A
  bf16* Eb   = (bf16*)(lds + 49152);   // [64][128]  bank-swizzled, phase B
  bf16* Pp   = (bf16*)(lds + 19456);   // [80][168]  softmax phase (over Aqu/Kt)
  float* wred  = (float*)(lds + 46336); // [80][4]
  float* rstat = (float*)(lds + 47616); // [80]

  const int idx = blockIdx.x;
  const int h = idx & 7, b = (idx >> 3) & 7, c = idx >> 6;
  const int u0 = c ? (c - 1) * 64 : 0;
  const int nut = c ? 128 : 64;
  const int ncols = c + 4 + nut;
  const int q0 = c ? 63 : 127;     // pos row p = q0 - m + jl
  const int tid = threadIdx.x, lane = tid & 63, wv = tid >> 6;
  const int quad = lane >> 4, l15 = lane & 15, key = l15 & 7;
  const int lenlim = lengths[b] - u0;
  const bool obf = (*flag != 0);

  // ---- stage V (152 rows, (k>>3)&7-swizzle) and PosSel (192 rows) ----
  {
    int lr = lane >> 3;
    int sbr = (lane & 7) ^ lr;
    for (int i = wv; i < 19; i += 4) {
      int row = i * 8 + lr;
      int g = gcol(row, c, u0, ncols);
      int sbv = (lane & 7) ^ (i & 7);
      const bf16* src = qkv + ((size_t)(g * 8 + b)) * NU + 1024 + h * 64 + sbv * 8;
      __builtin_amdgcn_global_load_lds((const AS1 void*)src, (AS3 void*)(Vs + i * 512), 16, 0, 0);
    }
    for (int i = wv; i < 24; i += 4) {
      int p = i * 8 + lr;
      const bf16* src = pos + (size_t)p * 512 + h * 64 + sbr * 8;
      __builtin_amdgcn_global_load_lds((const AS1 void*)src, (AS3 void*)(Psl + i * 512), 16, 0, 0);
    }
  }
  // ---- stage Aqu = q + pbu (80 rows), Aqv = q_utt + pbv (64 rows) ----
  for (int id = tid; id < 1152; id += 256) {
    bool isv = id >= 640;
    int lid = isv ? id - 640 : id;
    int m = lid >> 3, ec = lid & 7;
    int qrow;
    if (isv) qrow = 64 + 64 * c + m;
    else qrow = (m < 64) ? (64 + 64 * c + m)
              : (m < 68) ? (4 * c + (m - 64))
              : (m == 68) ? (1088 + c) : 0;
    const uint4 qa = *(const uint4*)(qkv + ((size_t)((qrow + 15) * 8 + b)) * NU + h * 64 + ec * 8);
    const uint4 ba = *(const uint4*)((isv ? pbv : pbu) + h * 64 + ec * 8);
    uint4 o;
    o.x = pk2(lo16(qa.x) + lo16(ba.x), hi16(qa.x) + hi16(ba.x));
    o.y = pk2(lo16(qa.y) + lo16(ba.y), hi16(qa.y) + hi16(ba.y));
    o.z = pk2(lo16(qa.z) + lo16(ba.z), hi16(qa.z) + hi16(ba.z));
    o.w = pk2(lo16(qa.w) + lo16(ba.w), hi16(qa.w) + hi16(ba.w));
    *(uint4*)((isv ? Aqv : Aqu) + m * 64 + (ec ^ (m & 7)) * 8) = o;
  }
  __syncthreads();  // s1

  // ---- E GEMM: E[64 x 192] = Aqv @ PosSel^T ----
  float4v eacc[4][3];
  #pragma unroll
  for (int mt = 0; mt < 4; ++mt)
    #pragma unroll
    for (int i = 0; i < 3; ++i) eacc[mt][i] = (float4v){0.f, 0.f, 0.f, 0.f};
  {
    short8v av[4][2];
    #pragma unroll
    for (int mt = 0; mt < 4; ++mt)
      #pragma unroll
      for (int ks = 0; ks < 2; ++ks)
        av[mt][ks] = *(const short8v*)&Aqv[(mt * 16 + l15) * 64 + ((ks * 4 + quad) ^ key) * 8];
    #pragma unroll
    for (int nti = 0; nti < 3; ++nti) {
      int nt = wv + nti * 4;
      short8v b0 = *(const short8v*)&Psl[(nt * 16 + l15) * 64 + (quad ^ key) * 8];
      short8v b1 = *(const short8v*)&Psl[(nt * 16 + l15) * 64 + ((4 + quad) ^ key) * 8];
      #pragma unroll
      for (int mt = 0; mt < 4; ++mt) {
        eacc[mt][nti] = __builtin_amdgcn_mfma_f32_16x16x32_bf16(av[mt][0], b0, eacc[mt][nti], 0, 0, 0);
        eacc[mt][nti] = __builtin_amdgcn_mfma_f32_16x16x32_bf16(av[mt][1], b1, eacc[mt][nti], 0, 0, 0);
      }
    }
  }
  __syncthreads();  // s2: Aqv/Psl dead

  // ---- stage K (row&7-swizzle) + scatter E into Eb (bank-swizzled) ----
  {
    int lr = lane >> 3, sbr = (lane & 7) ^ lr;
    for (int i = wv; i < 19; i += 4) {
      int row = i * 8 + lr;
      int g = gcol(row, c, u0, ncols);
      const bf16* src = qkv + ((size_t)(g * 8 + b)) * NU + 512 + h * 64 + sbr * 8;
      __builtin_amdgcn_global_load_lds((const AS1 void*)src, (AS3 void*)(Kt + i * 512), 16, 0, 0);
    }
  }
  #pragma unroll
  for (int nti = 0; nti < 3; ++nti) {
    int p = (wv + nti * 4) * 16 + l15;
    #pragma unroll
    for (int mt = 0; mt < 4; ++mt)
      #pragma unroll
      for (int r = 0; r < 4; ++r) {
        int m = mt * 16 + quad * 4 + r;
        int jl = p - q0 + m;
        if (jl >= 0 && jl < nut)
          Eb[m * 128 + (jl ^ (((m >> 2) & 7) << 4))] = __float2bfloat16(eacc[mt][nti][r]);
      }
  }
  __syncthreads();  // s3

  // ---- S GEMM: S[80 x 160] = Aqu @ K^T ----
  const int nnt = (wv < 2) ? 3 : 2;
  float4v sacc[5][3];
  #pragma unroll
  for (int mt = 0; mt < 5; ++mt)
    #pragma unroll
    for (int i = 0; i < 3; ++i) sacc[mt][i] = (float4v){0.f, 0.f, 0.f, 0.f};
  {
    short8v au[5][2];
    #pragma unroll
    for (int mt = 0; mt < 5; ++mt)
      #pragma unroll
      for (int ks = 0; ks < 2; ++ks)
        au[mt][ks] = *(const short8v*)&Aqu[(mt * 16 + l15) * 64 + ((ks * 4 + quad) ^ key) * 8];
    #pragma unroll
    for (int nti = 0; nti < 3; ++nti) {
      if (nti < nnt) {
        int nt = wv + nti * 4;
        short8v b0 = *(const short8v*)&Kt[(nt * 16 + l15) * 64 + (quad ^ key) * 8];
        short8v b1 = *(const short8v*)&Kt[(nt * 16 + l15) * 64 + ((4 + quad) ^ key) * 8];
        #pragma unroll
        for (int mt = 0; mt < 5; ++mt) {
          sacc[mt][nti] = __builtin_amdgcn_mfma_f32_16x16x32_bf16(au[mt][0], b0, sacc[mt][nti], 0, 0, 0);
          sacc[mt][nti] = __builtin_amdgcn_mfma_f32_16x16x32_bf16(au[mt][1], b1, sacc[mt][nti], 0, 0, 0);
        }
      }
    }
  }
  __syncthreads();  // s4: Aqu/Kt dead

  // ---- assembly: + E gather, masks, scale ----
  #pragma unroll
  for (int nti = 0; nti < 3; ++nti) {
    if (nti < nnt) {
      int colv = (wv + nti * 4) * 16 + l15;
      int jl = colv - (c + 4);
      bool cvalid = (colv < ncols) && !(jl >= 0 && jl >= lenlim);
      #pragma unroll
      for (int mt = 0; mt < 5; ++mt)
        #pragma unroll
        for (int r = 0; r < 4; ++r) {
          float s = sacc[mt][nti][r];
          if (cvalid) {
            if (mt < 4 && jl >= 0) {
              int m = mt * 16 + quad * 4 + r;
              s += __bfloat162float(Eb[m * 128 + (jl ^ (((m >> 2) & 7) << 4))]);
            }
            s *= 0.125f;
          } else s = -1e30f;
          sacc[mt][nti][r] = s;
        }
    }
  }

  // ---- softmax: row max ----
  {
    #pragma unroll
    for (int mt = 0; mt < 5; ++mt)
      #pragma unroll
      for (int r = 0; r < 4; ++r) {
        float v = -3e38f;
        #pragma unroll
        for (int nti = 0; nti < 3; ++nti)
          if (nti < nnt) v = fmaxf(v, sacc[mt][nti][r]);
        v = fmaxf(v, __shfl_xor(v, 1));
        v = fmaxf(v, __shfl_xor(v, 2));
        v = fmaxf(v, __shfl_xor(v, 4));
        v = fmaxf(v, __shfl_xor(v, 8));
        if (l15 == 0) wred[(mt * 16 + quad * 4 + r) * 4 + wv] = v;
      }
  }
  __syncthreads();  // s5
  if (tid < 80)
    rstat[tid] = fmaxf(fmaxf(wred[tid * 4], wred[tid * 4 + 1]),
                       fmaxf(wred[tid * 4 + 2], wred[tid * 4 + 3]));
  __syncthreads();  // s6

  // ---- softmax: exp, write P (bf16, stride 168), row sums ----
  {
    float rmx[5][4], rsum[5][4];
    #pragma unroll
    for (int mt = 0; mt < 5; ++mt)
      #pragma unroll
      for (int r = 0; r < 4; ++r) {
        rmx[mt][r] = rstat[mt * 16 + quad * 4 + r];
        rsum[mt][r] = 0.f;
      }
    #pragma unroll
    for (int nti = 0; nti < 3; ++nti) {
      if (nti < nnt) {
        int colv = (wv + nti * 4) * 16 + l15;
        #pragma unroll
        for (int mt = 0; mt < 5; ++mt)
          #pragma unroll
          for (int r = 0; r < 4; ++r) {
            float p = __expf(sacc[mt][nti][r] - rmx[mt][r]);
            Pp[(mt * 16 + quad * 4 + r) * 168 + colv] = __float2bfloat16(p);
            rsum[mt][r] += p;
          }
      }
    }
    #pragma unroll
    for (int mt = 0; mt < 5; ++mt)
      #pragma unroll
      for (int r = 0; r < 4; ++r) {
        float v = rsum[mt][r];
        v += __shfl_xor(v, 1);
        v += __shfl_xor(v, 2);
        v += __shfl_xor(v, 4);
        v += __shfl_xor(v, 8);
        if (l15 == 0) wred[(mt * 16 + quad * 4 + r) * 4 + wv] = v;
      }
  }
  __syncthreads();  // s7
  if (tid < 80)
    rstat[tid] = 1.f / (wred[tid * 4] + wred[tid * 4 + 1] + wred[tid * 4 + 2] + wred[tid * 4 + 3]);
  __syncthreads();  // s8

  // ---- PV GEMM: O[80 x 64] = P @ V ----
  const int kmax = (ncols + 31) >> 5;
  float4v oacc[5];
  #pragma unroll
  for (int mt = 0; mt < 5; ++mt) oacc[mt] = (float4v){0.f, 0.f, 0.f, 0.f};
  const int ehi = (wv * 16 + l15) >> 3, elo = l15 & 7;
  for (int ks = 0; ks < kmax; ++ks) {
    short8v bq;
    const int blk = ehi ^ ((ks * 4 + quad) & 7);
    #pragma unroll
    for (int j = 0; j < 8; ++j)
      bq[j] = ((const short*)Vs)[(ks * 32 + quad * 8 + j) * 64 + blk * 8 + elo];
    #pragma unroll
    for (int mt = 0; mt < 5; ++mt) {
      short8v af = *(const short8v*)&Pp[(mt * 16 + l15) * 168 + ks * 32 + quad * 8];
      oacc[mt] = __builtin_amdgcn_mfma_f32_16x16x32_bf16(af, bq, oacc[mt], 0, 0, 0);
    }
  }

  // ---- epilogue: rows m<68 -> attn; m==68 (summary) -> clipped d_out ----
  #pragma unroll
  for (int mt = 0; mt < 5; ++mt) {
    #pragma unroll
    for (int r = 0; r < 4; ++r) {
      int m = mt * 16 + quad * 4 + r;
      if (m >= 69) continue;
      float o = oacc[mt][r] * rstat[m];
      if (m < 68) {
        int qrow = (m < 64) ? (64 + 64 * c + m) : (4 * c + (m - 64));
        attn[((size_t)(qrow * 8 + b)) * 512 + h * 64 + wv * 16 + l15] = __float2bfloat16(o);
      } else {
        float v = fminf(fmaxf(o, -10.f), 10.f);
        size_t oi = (size_t)1088 * 8 * 512 + ((size_t)(c * 8 + b)) * 512 + h * 64 + wv * 16 + l15;
        if (obf) ((bf16*)dout)[oi] = __float2bfloat16(v);
        else     ((float*)dout)[oi] = v;
      }
    }
  }
}

static inline int cdiv(int a, int b) { return (a + b - 1) / b; }

extern "C" void kernel_launch(void* const* d_in, const int* in_sizes, int n_in,
                              void* d_out, int out_size, void* d_ws, size_t ws_size,
                              hipStream_t stream) {
  const void* utter = d_in[0];
  const int*  lens  = (const int*)d_in[1];
  const void* rctx  = d_in[2];
  const void* summ  = d_in[3];
  const void* memry = d_in[4];
  // d_in[5] attention_mask: analytic, never read
  const void* pose  = d_in[6];
  const void* W_kv  = d_in[7];
  const void* b_kv  = d_in[8];
  const void* W_q   = d_in[9];
  const void* b_q   = d_in[10];
  const void* W_out = d_in[11];
  const void* b_out = d_in[12];
  const void* W_pos = d_in[13];
  const void* pbu   = d_in[14];
  const void* pbv   = d_in[15];

  const unsigned SZ_MM = MM * BB * DD;   // 61440
  const unsigned SZ_RC = RR * BB * DD;   // 262144
  const unsigned SZ_UT = UU * BB * DD;   // 4194304
  const unsigned SZ_SM = SS * BB * DD;   // 65536
  const unsigned N_XU  = SZ_MM + SZ_RC + SZ_UT + SZ_SM;  // 4583424
  const unsigned SZ_PS = 191 * DD;       // 97792

  int*  flag = (int*)d_ws;
  bf16* base = (bf16*)((char*)d_ws + 64);
  unsigned off = 0;
  bf16* XU    = base + off; unsigned o_XU    = off; off += N_XU;
  bf16* posec = base + off; unsigned o_posec = off; off += 192 * DD;
  bf16* Wcat  = base + off; unsigned o_Wcat  = off; off += (unsigned)NU * DD;
  bf16* bcat  = base + off; unsigned o_bcat  = off; off += NU;
  bf16* Wout  = base + off; unsigned o_Wout  = off; off += DD * DD;
  bf16* bout  = base + off; unsigned o_bout  = off; off += DD;
  bf16* Wpos  = base + off; unsigned o_Wpos  = off; off += DD * DD;
  bf16* pbuc  = base + off; unsigned o_pbu   = off; off += DD;
  bf16* pbvc  = base + off; unsigned o_pbv   = off; off += DD;
  bf16* qkv   = base + off; off += (unsigned)(MU + 8) * NU;  // 8952 x 1536
  bf16* pos   = base + off; off += 192 * DD;
  bf16* attn  = base + off; off += QQ * BB * DD;

  // Fused pack: 14 segments (union X = [mem | rc | utt | summ])
  PackDesc pd;
  const void* srcs[14]  = {memry, rctx, utter, summ, pose,
                           W_q, W_kv, b_q, b_kv, W_out, b_out, W_pos, pbu, pbv};
  unsigned    soffs[14] = {0, 0, 0, 0, 896u * DD, 0, 0, 0, 0, 0, 0, 0, 0, 0};
  unsigned    doffs[14] = {o_XU, o_XU + SZ_MM, o_XU + SZ_MM + SZ_RC,
                           o_XU + SZ_MM + SZ_RC + SZ_UT, o_posec,
                           o_Wcat, o_Wcat + DD * DD, o_bcat, o_bcat + DD,
                           o_Wout, o_bout, o_Wpos, o_pbu, o_pbv};
  unsigned    ns[14]    = {SZ_MM, SZ_RC, SZ_UT, SZ_SM, SZ_PS,
                           DD * DD, 2 * DD * DD, DD, 2 * DD,
                           DD * DD, DD, DD * DD, DD, DD};
  unsigned cum = 0;
  for (int i = 0; i < 14; ++i) {
    pd.src[i] = srcs[i]; pd.srcoff[i] = soffs[i]; pd.dstoff[i] = doffs[i];
    pd.cum[i] = cum; cum += ns[i] / 8;
  }
  pd.src[14] = pbv; pd.srcoff[14] = 0; pd.dstoff[14] = o_pbv;
  pd.src[15] = pbv; pd.srcoff[15] = 0; pd.dstoff[15] = o_pbv;
  pd.cum[14] = cum; pd.cum[15] = cum; pd.cum[16] = cum;
  int nchunks = (int)cum;
  pack_all<<<dim3(cdiv(nchunks, 256)), dim3(256), 0, stream>>>(pd, base, utter, flag, nchunks);

  // fused QKV GEMM (8952 x 1536) + pos GEMM (191 x 512) in one dispatch
  GemmP gq{XU, Wcat, bcat, qkv, MU, NU, DD, nullptr};
  GemmP gp{posec, Wpos, nullptr, pos, 191, DD, DD, nullptr};
  gemm_dual<<<dim3(12, 71), dim3(256), 0, stream>>>(gq, gp, 70);

  // attention: one block per (c, b, h); writes attn rows + clipped summary rows
  attn_chunk<<<dim3(1024), dim3(256), 0, stream>>>(qkv, pos, pbuc, pbvc, lens, attn,
                                                   flag, d_out);

  // out_ru = attn[:1088] @ W_out^T + b_out
  GemmP go{attn, Wout, bout, d_out, (RR + UU) * BB, DD, DD, flag};
  gemm_dual<<<dim3(4, 68), dim3(256), 0, stream>>>(go, go, 68);
}